// Round 4
// baseline (549.386 us; speedup 1.0000x reference)
//
#include <hip/hip_runtime.h>
#include <hip/hip_bf16.h>
#include <stdint.h>

typedef __bf16 bf16;
typedef __attribute__((ext_vector_type(8))) __bf16 bf16x8;
typedef __attribute__((ext_vector_type(4))) float f32x4;

#define NEG_LN10K_32 (-0.28782313662425575f)   // -ln(10000)/32

// raw barriers with targeted waits (avoid __syncthreads' forced vmcnt(0) drain)
#define BAR_LGKM()   { asm volatile("s_waitcnt lgkmcnt(0)" ::: "memory"); __builtin_amdgcn_s_barrier(); }
#define BAR_VMLGKM() { asm volatile("s_waitcnt vmcnt(0) lgkmcnt(0)" ::: "memory"); __builtin_amdgcn_s_barrier(); }

__device__ __forceinline__ bf16x8 cvt8(f32x4 a, f32x4 b) {
    bf16x8 r;
    r[0] = (bf16)a[0]; r[1] = (bf16)a[1]; r[2] = (bf16)a[2]; r[3] = (bf16)a[3];
    r[4] = (bf16)b[0]; r[5] = (bf16)b[1]; r[6] = (bf16)b[2]; r[7] = (bf16)b[3];
    return r;
}

__device__ __forceinline__ void async_copy16(bf16* lds, const bf16* g) {
    __builtin_amdgcn_global_load_lds((const __attribute__((address_space(1))) void*)g,
                                     (__attribute__((address_space(3))) void*)lds, 16, 0, 0);
}

// ---------------------------------------------------------------------------
// Weight convert fp32->bf16, 6 segments of 1M elems. Grid (512,1,6).
// ---------------------------------------------------------------------------
__global__ __launch_bounds__(256) void wconv6(
    const float* __restrict__ s0, const float* __restrict__ s1, const float* __restrict__ s2,
    const float* __restrict__ s3, const float* __restrict__ s4, const float* __restrict__ s5,
    bf16* __restrict__ d0, bf16* __restrict__ d1, bf16* __restrict__ d2,
    bf16* __restrict__ d3, bf16* __restrict__ d4, bf16* __restrict__ d5)
{
    const int z = blockIdx.z;
    const float* src; bf16* dst;
    switch (z) {
        case 0: src = s0; dst = d0; break;
        case 1: src = s1; dst = d1; break;
        case 2: src = s2; dst = d2; break;
        case 3: src = s3; dst = d3; break;
        case 4: src = s4; dst = d4; break;
        default: src = s5; dst = d5; break;
    }
    const size_t i = ((size_t)blockIdx.x * 256 + threadIdx.x) * 8;
    *(bf16x8*)(dst + i) = cvt8(*(const f32x4*)(src + i), *(const f32x4*)(src + i + 4));
}

// ---------------------------------------------------------------------------
// Tiled transpose fp32->bf16: out[j,i] = in[i,j], 1024x1024. Grid (16,16,2).
// ---------------------------------------------------------------------------
__global__ __launch_bounds__(256) void prepT(
    const float* __restrict__ in0, const float* __restrict__ in1,
    bf16* __restrict__ out0, bf16* __restrict__ out1)
{
    const float* in = blockIdx.z ? in1 : in0;
    bf16* out       = blockIdx.z ? out1 : out0;
    __shared__ float tile[64 * 65];
    const int t  = threadIdx.x;
    const int i0 = blockIdx.y * 64, j0 = blockIdx.x * 64;
    const int r  = t >> 2, cg = (t & 3) * 16;
#pragma unroll
    for (int c = 0; c < 16; c += 4) {
        const f32x4 v = *(const f32x4*)(in + (size_t)(i0 + r) * 1024 + j0 + cg + c);
        tile[r * 65 + cg + c + 0] = v[0];
        tile[r * 65 + cg + c + 1] = v[1];
        tile[r * 65 + cg + c + 2] = v[2];
        tile[r * 65 + cg + c + 3] = v[3];
    }
    __syncthreads();
    bf16x8 o0v, o1v;
#pragma unroll
    for (int ii = 0; ii < 8; ++ii) {
        o0v[ii] = (bf16)tile[(cg + ii) * 65 + r];
        o1v[ii] = (bf16)tile[(cg + 8 + ii) * 65 + r];
    }
    bf16* dst = out + (size_t)(j0 + r) * 1024 + i0 + cg;
    *(bf16x8*)dst       = o0v;
    *(bf16x8*)(dst + 8) = o1v;
}

// ---------------------------------------------------------------------------
// GEMM: C[M,1024](bf16) = A @ W^T (+fp32 residual, +fused RoPE).
// 128x128 tile, BK=32, 4 waves of 64x64, mfma 16x16x32 bf16.
//
// Round 4 structure:
//  * B NEVER goes through LDS. W is 2MB, L2-resident, re-read by every block;
//    B-fragments are read straight from global (16B/lane, full 64B lines).
//    Deletes asyncB + its vmcnt(0) barrier drain (m233 stall) + half the
//    ds_read traffic. WF32 variant converts at use.
//  * Raw s_barrier + targeted waits (lgkm-only where no DMA), so in-flight
//    vmem spans barriers instead of being drained by __syncthreads.
//  * A path: !AF32 = double-buffered global_load_lds, asyncA(t+1) issued at
//    top of compute(t), ONE vmcnt(0)+lgkm barrier per step (drain is cheap:
//    issue-to-drain distance = full compute region).
//    AF32 = reg-staged; loadAreg(t+1) at top of compute(t), cvt+ds_write at
//    the end, ONE lgkm-only barrier per step (no vmem at the barrier at all).
//  * Bank swizzle on A kept from r2 (global source granule (t&3)^((t>>3)&3),
//    LDS dest linear, frag-read slot quad^((l16>>1)&3)).
// ---------------------------------------------------------------------------
template<int AF32, int WF32>
__global__ __launch_bounds__(256) void gemm_bt(
    const void* __restrict__ A0v, const void* __restrict__ A1v, const void* __restrict__ A2v,
    const void* __restrict__ W0v, const void* __restrict__ W1v, const void* __restrict__ W2v,
    bf16* __restrict__ C0, bf16* __restrict__ C1, bf16* __restrict__ C2,
    const float* __restrict__ R0, int rope_mask)
{
    const int z = blockIdx.z;
    const void* Av = (z == 0) ? A0v : ((z == 1) ? A1v : A2v);
    const void* Wp = (z == 0) ? W0v : ((z == 1) ? W1v : W2v);
    bf16*       C  = (z == 0) ? C0 : ((z == 1) ? C1 : C2);
    const float* R = (z == 0) ? R0 : nullptr;
    const bool doRope = ((rope_mask >> z) & 1) != 0;

    __shared__ __attribute__((aligned(16))) bf16 sA[2][128 * 32];   // 16 KB

    const int t    = threadIdx.x;
    const int w    = t >> 6;
    const int lane = t & 63;
    const int l16  = lane & 15;
    const int quad = lane >> 4;
    const int wrow = w >> 1;
    const int wcol = w & 1;

    int m0, n0;
    if (gridDim.y == 64) {   // M=8192: XCD stripe swizzle (xcd owns 1024 rows)
        const int fs   = blockIdx.y * 8 + blockIdx.x;
        const int xcd  = fs & 7;
        const int slot = fs >> 3;
        m0 = ((xcd << 3) | (slot >> 3)) * 128;
        n0 = (slot & 7) * 128;
    } else {                 // small (weight-precompute) grids: plain mapping
        m0 = blockIdx.y * 128;
        n0 = blockIdx.x * 128;
    }

    // A staging offsets: global source granule pre-swizzled (LDS dest linear)
    const int sgr = ((t & 3) ^ ((t >> 3) & 3)) * 8;
    const size_t aOff = (size_t)(m0 + (t >> 2)) * 1024 + sgr;
    // frag-read slot: quad ^ (row>>1)&3  (per-lane constant)
    const int qs = (quad ^ ((l16 >> 1) & 3)) * 8;

    // B row base for this lane (natural layout, no swizzle — no LDS for B)
    const size_t bBase = (size_t)(n0 + wcol * 64 + l16) * 1024 + quad * 8;

    f32x4 arg[4];   // AF32 reg staging (liveness confined to one compute region)

    auto loadAreg = [&](int k0) {
        const float* g = (const float*)Av;
        arg[0] = *(const f32x4*)(g + aOff + k0);
        arg[1] = *(const f32x4*)(g + aOff + k0 + 4);
        arg[2] = *(const f32x4*)(g + aOff + 65536 + k0);
        arg[3] = *(const f32x4*)(g + aOff + 65536 + k0 + 4);
    };
    auto writeAreg = [&](int b) {
        *(bf16x8*)&sA[b][t * 8]        = cvt8(arg[0], arg[1]);
        *(bf16x8*)&sA[b][t * 8 + 2048] = cvt8(arg[2], arg[3]);
    };
    auto stageAasync = [&](int k0, int b) {
        const bf16* g = (const bf16*)Av;
        async_copy16(&sA[b][w * 512],        g + aOff + k0);
        async_copy16(&sA[b][w * 512 + 2048], g + aOff + 65536 + k0);
    };

    f32x4 acc[4][4];
#pragma unroll
    for (int i = 0; i < 4; ++i)
#pragma unroll
        for (int j = 0; j < 4; ++j)
            acc[i][j] = (f32x4){0.f, 0.f, 0.f, 0.f};

    // ---- prologue: tile 0 into buf 0 ----
    if constexpr (AF32) {
        loadAreg(0);
        writeAreg(0);                 // compiler inserts the vmcnt wait
        BAR_LGKM();
    } else {
        stageAasync(0, 0);
        BAR_VMLGKM();
    }

    for (int k0 = 0; k0 < 1024; k0 += 32) {
        const int buf = (k0 >> 5) & 1;
        const int nb  = buf ^ 1;
        const bool more = (k0 + 32 < 1024);

        // issue next tile's A traffic first (latency hides under this step)
        if (more) {
            if constexpr (AF32) loadAreg(k0 + 32);
            else                stageAasync(k0 + 32, nb);
        }

        // B fragments straight from global (L2-resident weight panel)
        bf16x8 bw[4];
#pragma unroll
        for (int ni = 0; ni < 4; ++ni) {
            if constexpr (WF32) {
                const float* p = (const float*)Wp + bBase + ni * 16384 + k0;
                bw[ni] = cvt8(*(const f32x4*)p, *(const f32x4*)(p + 4));
            } else {
                bw[ni] = *(const bf16x8*)((const bf16*)Wp + bBase + ni * 16384 + k0);
            }
        }

        // A fragments from LDS + MFMA
#pragma unroll
        for (int mi = 0; mi < 4; ++mi) {
            const bf16x8 af = *(const bf16x8*)&sA[buf][(wrow * 64 + mi * 16 + l16) * 32 + qs];
#pragma unroll
            for (int ni = 0; ni < 4; ++ni)
                acc[mi][ni] = __builtin_amdgcn_mfma_f32_16x16x32_bf16(af, bw[ni], acc[mi][ni], 0, 0, 0);
        }

        // AF32: convert+write next tile into the other buffer (reads of nb
        // finished last step; the barrier below publishes the writes)
        if (more) {
            if constexpr (AF32) writeAreg(nb);
        }

        if constexpr (AF32) { BAR_LGKM(); }        // no vmem at the barrier
        else                { BAR_VMLGKM(); }      // drain asyncA(t+1), issued a region ago
    }

    if (doRope) {
        const float bb = (float)(m0 >> 10);
        float s0, c0v, s1, c1v;
        sincosf(bb * expf((float)l16 * NEG_LN10K_32), &s0, &c0v);
        sincosf(bb * expf((float)(16 + l16) * NEG_LN10K_32), &s1, &c1v);
#pragma unroll
        for (int mi = 0; mi < 4; ++mi) {
#pragma unroll
            for (int r = 0; r < 4; ++r) {
                float x1 = acc[mi][0][r], x2 = acc[mi][2][r];
                acc[mi][0][r] = x1 * c0v - x2 * s0;
                acc[mi][2][r] = x2 * c0v + x1 * s0;
                x1 = acc[mi][1][r]; x2 = acc[mi][3][r];
                acc[mi][1][r] = x1 * c1v - x2 * s1;
                acc[mi][3][r] = x2 * c1v + x1 * s1;
            }
        }
    }

#pragma unroll
    for (int mi = 0; mi < 4; ++mi) {
#pragma unroll
        for (int ni = 0; ni < 4; ++ni) {
            const int col = n0 + wcol * 64 + ni * 16 + l16;
#pragma unroll
            for (int r = 0; r < 4; ++r) {
                const int row = m0 + wrow * 64 + mi * 16 + quad * 4 + r;
                float v = acc[mi][ni][r];
                if (R) v += R[(size_t)row * 1024 + col];
                C[(size_t)row * 1024 + col] = (bf16)v;
            }
        }
    }
}

// ---------------------------------------------------------------------------
// Flash attention, O written IN-PLACE over QP (block (qt,h) touches only its
// own row x col slice of QP — race-free). No running max (|score| <~ 1.5:
// m fixed at 0), denominator deferred: per-lane partial sums, one cross-lane
// reduce at the end. P-strip sync is wave-local (lgkmcnt), not a barrier.
// Round 4: the two __syncthreads are now lgkm-only raw barriers, so the K/V
// register prefetch (r3, T14) actually stays in flight across the barrier
// instead of being drained by __syncthreads' implied vmcnt(0).
// ---------------------------------------------------------------------------
__global__ __launch_bounds__(256) void attn_kernel(
    bf16* __restrict__ QP, const bf16* __restrict__ KP, const bf16* __restrict__ VP)
{
    const int fs   = blockIdx.y * 8 + blockIdx.x;
    const int xcd  = fs & 7;
    const int slot = fs >> 3;
    const int qt   = slot & 7;
    const int bh   = (xcd << 4) | (slot >> 3);
    const int tb = (bh >> 4) << 10;
    const int fb = (bh & 15) << 6;

    __shared__ __attribute__((aligned(16))) bf16 sK0[64 * 32];
    __shared__ __attribute__((aligned(16))) bf16 sK1[64 * 32];
    __shared__ __attribute__((aligned(16))) bf16 sVt[64 * 72];
    __shared__ __attribute__((aligned(16))) bf16 sP[4][32 * 72];

    const int t    = threadIdx.x;
    const int w    = t >> 6;
    const int lane = t & 63;
    const int l16  = lane & 15;
    const int quad = lane >> 4;

    const int sgr = ((t & 3) ^ ((t >> 3) & 3)) * 8;       // staging granule (swizzled)
    const int qs  = (quad ^ ((l16 >> 1) & 3)) * 8;        // frag-read slot

    bf16x8 qf[2][2];
#pragma unroll
    for (int mi = 0; mi < 2; ++mi)
#pragma unroll
        for (int kd = 0; kd < 2; ++kd)
            qf[mi][kd] = *(const bf16x8*)&QP[(size_t)(tb + qt * 128 + w * 32 + mi * 16 + l16) * 1024
                                            + fb + kd * 32 + quad * 8];

    f32x4 oacc[2][4];
#pragma unroll
    for (int i = 0; i < 2; ++i)
#pragma unroll
        for (int j = 0; j < 4; ++j)
            oacc[i][j] = (f32x4){0.f, 0.f, 0.f, 0.f};
    float psum[2][4];
#pragma unroll
    for (int i = 0; i < 2; ++i)
#pragma unroll
        for (int r = 0; r < 4; ++r) psum[i][r] = 0.f;

    auto ldK = [&](int kt, bf16x8& a, bf16x8& b) {
        const bf16* kRow = KP + (size_t)(tb + kt * 64 + (t >> 2)) * 1024 + fb + sgr;
        a = *(const bf16x8*)(kRow);
        b = *(const bf16x8*)(kRow + 32);
    };
    auto ldV = [&](int kt, bf16x8& a, bf16x8& b) {
        const bf16* vRow = VP + (size_t)(tb + kt * 64 + lane) * 1024 + fb;
        a = *(const bf16x8*)(vRow + w * 8);
        b = *(const bf16x8*)(vRow + (w + 4) * 8);
    };

    bf16x8 vk0, vk1, vv0, vv1;
    ldK(0, vk0, vk1);
    ldV(0, vv0, vv1);

    for (int kt = 0; kt < 16; ++kt) {
        BAR_LGKM();                       // prior PV reads done; vmem stays in flight
        *(bf16x8*)&sK0[t * 8] = vk0;
        *(bf16x8*)&sK1[t * 8] = vk1;
#pragma unroll
        for (int j = 0; j < 8; ++j) sVt[(w * 8 + j) * 72 + lane]       = vv0[j];
#pragma unroll
        for (int j = 0; j < 8; ++j) sVt[((w + 4) * 8 + j) * 72 + lane] = vv1[j];

        // prefetch kt+1 (completes under this iteration's compute)
        bf16x8 nk0, nk1, nv0, nv1;
        const bool more = (kt + 1 < 16);
        if (more) {
            ldK(kt + 1, nk0, nk1);
            ldV(kt + 1, nv0, nv1);
        }
        BAR_LGKM();                       // publish LDS writes; prefetch NOT drained

        bf16x8 kf[4][2];
#pragma unroll
        for (int ni = 0; ni < 4; ++ni) {
            kf[ni][0] = *(const bf16x8*)&sK0[(ni * 16 + l16) * 32 + qs];
            kf[ni][1] = *(const bf16x8*)&sK1[(ni * 16 + l16) * 32 + qs];
        }
        f32x4 sfr[2][4];
#pragma unroll
        for (int mi = 0; mi < 2; ++mi)
#pragma unroll
            for (int ni = 0; ni < 4; ++ni) {
                f32x4 a = (f32x4){0.f, 0.f, 0.f, 0.f};
                a = __builtin_amdgcn_mfma_f32_16x16x32_bf16(qf[mi][0], kf[ni][0], a, 0, 0, 0);
                a = __builtin_amdgcn_mfma_f32_16x16x32_bf16(qf[mi][1], kf[ni][1], a, 0, 0, 0);
                sfr[mi][ni] = a * 0.125f;
            }

        // p = exp(s); accumulate per-lane denominator partials (no shuffles)
#pragma unroll
        for (int mi = 0; mi < 2; ++mi)
#pragma unroll
            for (int ni = 0; ni < 4; ++ni)
#pragma unroll
                for (int r = 0; r < 4; ++r) {
                    const float p = __expf(sfr[mi][ni][r]);
                    sfr[mi][ni][r] = p;
                    psum[mi][r] += p;
                }

        // P: C-layout -> A-operand layout via wave-private LDS strip
        bf16* sPw = &sP[w][0];
#pragma unroll
        for (int mi = 0; mi < 2; ++mi)
#pragma unroll
            for (int ni = 0; ni < 4; ++ni)
#pragma unroll
                for (int r = 0; r < 4; ++r)
                    sPw[(mi * 16 + quad * 4 + r) * 72 + ni * 16 + l16] = (bf16)sfr[mi][ni][r];
        asm volatile("s_waitcnt lgkmcnt(0)" ::: "memory");   // wave-local W->R order

#pragma unroll
        for (int kd = 0; kd < 2; ++kd) {
            bf16x8 pf[2], vf[4];
#pragma unroll
            for (int mi = 0; mi < 2; ++mi)
                pf[mi] = *(const bf16x8*)&sPw[(mi * 16 + l16) * 72 + kd * 32 + quad * 8];
#pragma unroll
            for (int di = 0; di < 4; ++di)
                vf[di] = *(const bf16x8*)&sVt[(di * 16 + l16) * 72 + kd * 32 + quad * 8];
#pragma unroll
            for (int mi = 0; mi < 2; ++mi)
#pragma unroll
                for (int di = 0; di < 4; ++di)
                    oacc[mi][di] = __builtin_amdgcn_mfma_f32_16x16x32_bf16(pf[mi], vf[di], oacc[mi][di], 0, 0, 0);
        }

        if (more) { vk0 = nk0; vk1 = nk1; vv0 = nv0; vv1 = nv1; }
    }

#pragma unroll
    for (int mi = 0; mi < 2; ++mi) {
#pragma unroll
        for (int r = 0; r < 4; ++r) {
            float l = psum[mi][r];
            l += __shfl_xor(l, 1);
            l += __shfl_xor(l, 2);
            l += __shfl_xor(l, 4);
            l += __shfl_xor(l, 8);
            const float inv = 1.f / l;
            const int row = tb + qt * 128 + w * 32 + mi * 16 + quad * 4 + r;
#pragma unroll
            for (int di = 0; di < 4; ++di) {
                const int col = fb + di * 16 + l16;
                QP[(size_t)row * 1024 + col] = (bf16)(oacc[mi][di][r] * inv);
            }
        }
    }
}

// ---------------------------------------------------------------------------
// LayerNorm: bf16 in, fp32 gamma/beta, fp32 out. One 128-thread block per row.
// ---------------------------------------------------------------------------
__global__ __launch_bounds__(128) void ln_kernel(const bf16* __restrict__ X,
                                                 const float* __restrict__ G,
                                                 const float* __restrict__ Bt,
                                                 float* __restrict__ Y)
{
    const int row = blockIdx.x;
    const int t   = threadIdx.x;
    const size_t base = (size_t)row * 1024 + t * 8;
    const bf16x8 xv = *(const bf16x8*)(X + base);
    float f[8];
    float s = 0.f, s2 = 0.f;
#pragma unroll
    for (int j = 0; j < 8; ++j) { f[j] = (float)xv[j]; s += f[j]; s2 += f[j] * f[j]; }
#pragma unroll
    for (int off = 1; off < 64; off <<= 1) { s += __shfl_xor(s, off); s2 += __shfl_xor(s2, off); }
    __shared__ float ss[2], ssq[2];
    if ((t & 63) == 0) { ss[t >> 6] = s; ssq[t >> 6] = s2; }
    __syncthreads();
    s  = ss[0] + ss[1];
    s2 = ssq[0] + ssq[1];
    const float mu  = s * (1.f / 1024.f);
    const float inv = rsqrtf(s2 * (1.f / 1024.f) - mu * mu + 1e-5f);
    const f32x4 g0 = *(const f32x4*)(G + t * 8);
    const f32x4 g1 = *(const f32x4*)(G + t * 8 + 4);
    const f32x4 b0 = *(const f32x4*)(Bt + t * 8);
    const f32x4 b1 = *(const f32x4*)(Bt + t * 8 + 4);
    f32x4 y0, y1;
#pragma unroll
    for (int j = 0; j < 4; ++j) {
        y0[j] = (f[j]     - mu) * inv * g0[j] + b0[j];
        y1[j] = (f[j + 4] - mu) * inv * g1[j] + b1[j];
    }
    *(f32x4*)(Y + base)     = y0;
    *(f32x4*)(Y + base + 4) = y1;
}

// ---------------------------------------------------------------------------
extern "C" void kernel_launch(void* const* d_in, const int* in_sizes, int n_in,
                              void* d_out, int out_size, void* d_ws, size_t ws_size,
                              hipStream_t stream)
{
    const float* query = (const float*)d_in[0];
    const float* key   = (const float*)d_in[1];
    const float* value = (const float*)d_in[2];
    const float* Wq    = (const float*)d_in[3];
    const float* Wk    = (const float*)d_in[4];
    const float* Wv    = (const float*)d_in[5];
    const float* ipw   = (const float*)d_in[6];
    const float* opw   = (const float*)d_in[7];
    const float* pw    = (const float*)d_in[8];
    const float* gamma = (const float*)d_in[9];
    const float* beta  = (const float*)d_in[10];

    const size_t ACT = (size_t)8192 * 1024;   // act slot: 8.39M elems (16.78 MB)
    const size_t MW  = 1048576;               // weight matrix: 1M elems (2 MB)
    bf16* o0 = (bf16*)d_out;                  // d_out fp32 = 2 bf16 act slots
    bf16* o1 = o0 + ACT;

    dim3 blk(256);
    dim3 g3(8, 64, 3);
    dim3 g1(8, 64, 1);
    dim3 ga(8, 128);

    // Full tier needs 6 weight mats + 2 act slots = 45.6 MB (round 4 proved >=50.3)
    const bool full = ws_size >= (6 * MW + 2 * ACT) * sizeof(bf16);

    if (full) {
        bf16* wq  = (bf16*)d_ws;        // persistent bf16 weights
        bf16* wk  = wq + MW;
        bf16* wqa = wq + 2 * MW;
        bf16* wka = wq + 3 * MW;
        bf16* Fv  = wq + 4 * MW;        // fused Wva@Wv
        bf16* Fo  = wq + 5 * MW;        // fused pw@opw
        bf16* sltA = wq + 6 * MW;       // act slot A
        bf16* sltB = sltA + ACT;        // act slot B
        // transients (dead before slots hold activations)
        bf16* tWva = sltA;              // A-operands for precompute
        bf16* tpw  = sltA + MW;
        bf16* WvT  = sltB;              // transposed B-operands
        bf16* opwT = sltB + MW;

        // 0) weight converts + transposes
        wconv6<<<dim3(512, 1, 6), blk, 0, stream>>>(
            Wq, Wk, ipw, ipw + MW, ipw + 2 * MW, pw,
            wq, wk, wqa, wka, tWva, tpw);
        prepT<<<dim3(16, 16, 2), blk, 0, stream>>>(Wv, opw, WvT, opwT);
        // 1) precompute fused weights: Fv = Wva@Wv, Fo = pw@opw
        gemm_bt<0, 0><<<dim3(8, 8, 2), blk, 0, stream>>>(
            tWva, tpw, tpw, WvT, opwT, opwT, Fv, Fo, Fo, nullptr, 0);
        // 2) q(rope)=sltA, k(rope)=sltB, vp = value@Fv^T = o0 (skips v intermediate)
        gemm_bt<1, 0><<<g3, blk, 0, stream>>>(query, key, value, wq, wk, Fv,
                                              sltA, sltB, o0, nullptr, 0b011);
        // 3) qp = q @ Wqa^T   (sltA -> o1)
        gemm_bt<0, 0><<<g1, blk, 0, stream>>>(sltA, sltA, sltA, wqa, wqa, wqa,
                                              o1, o1, o1, nullptr, 0);
        // 4) kp = k @ Wka^T   (sltB -> sltA)
        gemm_bt<0, 0><<<g1, blk, 0, stream>>>(sltB, sltB, sltB, wka, wka, wka,
                                              sltA, sltA, sltA, nullptr, 0);
        // 5) attention: qp=o1 (O in-place), kp=sltA, vp=o0
        attn_kernel<<<ga, blk, 0, stream>>>(o1, sltA, o0);
        // 6) x = o @ Fo^T + query (o1 -> sltB)  [skips o2 intermediate]
        gemm_bt<0, 0><<<g1, blk, 0, stream>>>(o1, o1, o1, Fo, Fo, Fo,
                                              sltB, sltB, sltB, query, 0);
        // 7) LayerNorm -> d_out fp32
        ln_kernel<<<8192, 128, 0, stream>>>(sltB, gamma, beta, (float*)d_out);
    } else {
        // 33.5 MB fallback: round-3 schedule, fp32 weights, attn in-place
        bf16* b0 = (bf16*)d_ws;
        bf16* b1 = b0 + ACT;
        gemm_bt<1, 1><<<g3, blk, 0, stream>>>(query, key, value, Wq, Wk, Wv,
                                              b0, b1, o0, nullptr, 0b011);
        gemm_bt<0, 1><<<g1, blk, 0, stream>>>(o0, o0, o0, ipw + 2 * MW, ipw, ipw,
                                              o1, o1, o1, nullptr, 0);
        gemm_bt<0, 1><<<g1, blk, 0, stream>>>(b0, b0, b0, ipw, ipw, ipw,
                                              o0, o0, o0, nullptr, 0);
        gemm_bt<0, 1><<<g1, blk, 0, stream>>>(b1, b1, b1, ipw + MW, ipw, ipw,
                                              b0, b0, b0, nullptr, 0);
        attn_kernel<<<ga, blk, 0, stream>>>(o0, b0, o1);   // o -> o0 in-place
        gemm_bt<0, 1><<<g1, blk, 0, stream>>>(o0, o0, o0, opw, opw, opw,
                                              b0, b0, b0, nullptr, 0);
        gemm_bt<0, 1><<<g1, blk, 0, stream>>>(b0, b0, b0, pw, pw, pw,
                                              b1, b1, b1, query, 0);
        ln_kernel<<<8192, 128, 0, stream>>>(b1, gamma, beta, (float*)d_out);
    }
}

// Round 5
// 461.676 us; speedup vs baseline: 1.1900x; 1.1900x over previous
//
#include <hip/hip_runtime.h>
#include <hip/hip_bf16.h>
#include <stdint.h>

typedef __bf16 bf16;
typedef __attribute__((ext_vector_type(8))) __bf16 bf16x8;
typedef __attribute__((ext_vector_type(4))) float f32x4;

#define NEG_LN10K_32 (-0.28782313662425575f)   // -ln(10000)/32

__device__ __forceinline__ bf16x8 cvt8(f32x4 a, f32x4 b) {
    bf16x8 r;
    r[0] = (bf16)a[0]; r[1] = (bf16)a[1]; r[2] = (bf16)a[2]; r[3] = (bf16)a[3];
    r[4] = (bf16)b[0]; r[5] = (bf16)b[1]; r[6] = (bf16)b[2]; r[7] = (bf16)b[3];
    return r;
}

__device__ __forceinline__ void async_copy16(bf16* lds, const bf16* g) {
    __builtin_amdgcn_global_load_lds((const __attribute__((address_space(1))) void*)g,
                                     (__attribute__((address_space(3))) void*)lds, 16, 0, 0);
}

// ---------------------------------------------------------------------------
// Weight convert fp32->bf16, 6 segments of 1M elems. Grid (512,1,6).
// ---------------------------------------------------------------------------
__global__ __launch_bounds__(256) void wconv6(
    const float* __restrict__ s0, const float* __restrict__ s1, const float* __restrict__ s2,
    const float* __restrict__ s3, const float* __restrict__ s4, const float* __restrict__ s5,
    bf16* __restrict__ d0, bf16* __restrict__ d1, bf16* __restrict__ d2,
    bf16* __restrict__ d3, bf16* __restrict__ d4, bf16* __restrict__ d5)
{
    const int z = blockIdx.z;
    const float* src; bf16* dst;
    switch (z) {
        case 0: src = s0; dst = d0; break;
        case 1: src = s1; dst = d1; break;
        case 2: src = s2; dst = d2; break;
        case 3: src = s3; dst = d3; break;
        case 4: src = s4; dst = d4; break;
        default: src = s5; dst = d5; break;
    }
    const size_t i = ((size_t)blockIdx.x * 256 + threadIdx.x) * 8;
    *(bf16x8*)(dst + i) = cvt8(*(const f32x4*)(src + i), *(const f32x4*)(src + i + 4));
}

// ---------------------------------------------------------------------------
// Tiled transpose fp32->bf16: out[j,i] = in[i,j], 1024x1024. Grid (16,16,2).
// ---------------------------------------------------------------------------
__global__ __launch_bounds__(256) void prepT(
    const float* __restrict__ in0, const float* __restrict__ in1,
    bf16* __restrict__ out0, bf16* __restrict__ out1)
{
    const float* in = blockIdx.z ? in1 : in0;
    bf16* out       = blockIdx.z ? out1 : out0;
    __shared__ float tile[64 * 65];
    const int t  = threadIdx.x;
    const int i0 = blockIdx.y * 64, j0 = blockIdx.x * 64;
    const int r  = t >> 2, cg = (t & 3) * 16;
#pragma unroll
    for (int c = 0; c < 16; c += 4) {
        const f32x4 v = *(const f32x4*)(in + (size_t)(i0 + r) * 1024 + j0 + cg + c);
        tile[r * 65 + cg + c + 0] = v[0];
        tile[r * 65 + cg + c + 1] = v[1];
        tile[r * 65 + cg + c + 2] = v[2];
        tile[r * 65 + cg + c + 3] = v[3];
    }
    __syncthreads();
    bf16x8 o0v, o1v;
#pragma unroll
    for (int ii = 0; ii < 8; ++ii) {
        o0v[ii] = (bf16)tile[(cg + ii) * 65 + r];
        o1v[ii] = (bf16)tile[(cg + 8 + ii) * 65 + r];
    }
    bf16* dst = out + (size_t)(j0 + r) * 1024 + i0 + cg;
    *(bf16x8*)dst       = o0v;
    *(bf16x8*)(dst + 8) = o1v;
}

// ---------------------------------------------------------------------------
// GEMM: C[M,1024](bf16) = A @ W^T (+fp32 residual, +fused RoPE).
//
// Round 5: retile 128x128 -> 128x64 (wave tile 32x64, acc[2][4]=32 AGPR).
// Evidence: r2's best structure was REGISTER-occupancy-bound — 80 VGPR +
// 64 AGPR = 144/wave -> floor(512/144) = 3 waves/SIMD (measured Occ 29-33%);
// and the g1 grids (512 blocks) were grid-limited at 2 blocks/CU. Halving
// the accumulator doubles available TLP (target 5 waves/SIMD) and doubles
// the grid (1024 blocks/slice = 4 blocks/CU co-resident for g1).
// Structure otherwise IDENTICAL to r2 (the best so far): 2x __syncthreads
// per K-step, global_load_lds staging (linear dest), pre-swizzled global
// source granule (t&3)^((t>>3)&3), frag-read slot quad^((l16>>1)&3)
// (bank-conflict-free, verified 0 in r2), XCD swizzle = xcd owns one
// 1024-row batch band (A-band 2MB + W 2MB L2-resident per XCD).
// RoPE pairs (d,d+32) = (ni, ni+2) stay inside the 64-col wave tile.
// ---------------------------------------------------------------------------
template<int AF32, int WF32>
__global__ __launch_bounds__(256) void gemm_bt(
    const void* __restrict__ A0v, const void* __restrict__ A1v, const void* __restrict__ A2v,
    const void* __restrict__ W0v, const void* __restrict__ W1v, const void* __restrict__ W2v,
    bf16* __restrict__ C0, bf16* __restrict__ C1, bf16* __restrict__ C2,
    const float* __restrict__ R0, int rope_mask)
{
    const int z = blockIdx.z;
    const void* Av = (z == 0) ? A0v : ((z == 1) ? A1v : A2v);
    const void* Wp = (z == 0) ? W0v : ((z == 1) ? W1v : W2v);
    bf16*       C  = (z == 0) ? C0 : ((z == 1) ? C1 : C2);
    const float* R = (z == 0) ? R0 : nullptr;
    const bool doRope = ((rope_mask >> z) & 1) != 0;

    __shared__ __attribute__((aligned(16))) bf16 sA[128 * 32];   // 8 KB
    __shared__ __attribute__((aligned(16))) bf16 sB[64 * 32];    // 4 KB

    const int t    = threadIdx.x;
    const int w    = t >> 6;          // wave 0..3 = 32-row strip
    const int lane = t & 63;
    const int l16  = lane & 15;
    const int quad = lane >> 4;

    int m0, n0;
    if (gridDim.y == 64) {   // M=8192 grids: XCD swizzle, xcd owns 1024 rows
        const int fs   = blockIdx.y * 16 + blockIdx.x;   // 0..1023
        const int xcd  = fs & 7;
        const int slot = fs >> 3;                        // 0..127
        m0 = ((xcd << 3) | (slot >> 4)) * 128;
        n0 = (slot & 15) * 64;
    } else {                 // small (weight-precompute) grids: plain mapping
        m0 = blockIdx.y * 128;
        n0 = blockIdx.x * 64;
    }

    // staging offsets: global source granule pre-swizzled (LDS dest linear)
    const int sgr = ((t & 3) ^ ((t >> 3) & 3)) * 8;
    const size_t aOff = (size_t)(m0 + (t >> 2)) * 1024 + sgr;   // rows m0..m0+63 (+64)
    const size_t wOff = (size_t)(n0 + (t >> 2)) * 1024 + sgr;   // rows n0..n0+63
    // frag-read slot: quad ^ (row>>1)&3  (per-lane constant)
    const int qs = (quad ^ ((l16 >> 1) & 3)) * 8;

    f32x4 acc[2][4];
#pragma unroll
    for (int i = 0; i < 2; ++i)
#pragma unroll
        for (int j = 0; j < 4; ++j)
            acc[i][j] = (f32x4){0.f, 0.f, 0.f, 0.f};

    for (int k0 = 0; k0 < 1024; k0 += 32) {
        bf16x8 va0, va1, vb0;
        if (AF32) {
            const float* g = (const float*)Av;
            va0 = cvt8(*(const f32x4*)(g + aOff + k0),             *(const f32x4*)(g + aOff + k0 + 4));
            va1 = cvt8(*(const f32x4*)(g + aOff + 64 * 1024 + k0), *(const f32x4*)(g + aOff + 64 * 1024 + k0 + 4));
        }
        if (WF32) {
            const float* g = (const float*)Wp;
            vb0 = cvt8(*(const f32x4*)(g + wOff + k0), *(const f32x4*)(g + wOff + k0 + 4));
        }
        __syncthreads();
        if (AF32) {
            *(bf16x8*)&sA[t * 8]        = va0;
            *(bf16x8*)&sA[t * 8 + 2048] = va1;
        } else {
            const bf16* g = (const bf16*)Av;
            async_copy16(sA + w * 512,        g + aOff + k0);
            async_copy16(sA + w * 512 + 2048, g + aOff + 64 * 1024 + k0);
        }
        if (WF32) {
            *(bf16x8*)&sB[t * 8] = vb0;
        } else {
            const bf16* g = (const bf16*)Wp;
            async_copy16(sB + w * 512, g + wOff + k0);
        }
        __syncthreads();

        bf16x8 bw[4];
#pragma unroll
        for (int ni = 0; ni < 4; ++ni)
            bw[ni] = *(const bf16x8*)&sB[(ni * 16 + l16) * 32 + qs];
#pragma unroll
        for (int mi = 0; mi < 2; ++mi) {
            const bf16x8 af = *(const bf16x8*)&sA[(w * 32 + mi * 16 + l16) * 32 + qs];
#pragma unroll
            for (int ni = 0; ni < 4; ++ni)
                acc[mi][ni] = __builtin_amdgcn_mfma_f32_16x16x32_bf16(af, bw[ni], acc[mi][ni], 0, 0, 0);
        }
    }

    if (doRope) {
        const float bb = (float)(m0 >> 10);
        float s0, c0v, s1, c1v;
        sincosf(bb * expf((float)l16 * NEG_LN10K_32), &s0, &c0v);
        sincosf(bb * expf((float)(16 + l16) * NEG_LN10K_32), &s1, &c1v);
#pragma unroll
        for (int mi = 0; mi < 2; ++mi) {
#pragma unroll
            for (int r = 0; r < 4; ++r) {
                float x1 = acc[mi][0][r], x2 = acc[mi][2][r];
                acc[mi][0][r] = x1 * c0v - x2 * s0;
                acc[mi][2][r] = x2 * c0v + x1 * s0;
                x1 = acc[mi][1][r]; x2 = acc[mi][3][r];
                acc[mi][1][r] = x1 * c1v - x2 * s1;
                acc[mi][3][r] = x2 * c1v + x1 * s1;
            }
        }
    }

#pragma unroll
    for (int mi = 0; mi < 2; ++mi) {
#pragma unroll
        for (int ni = 0; ni < 4; ++ni) {
            const int col = n0 + ni * 16 + l16;
#pragma unroll
            for (int r = 0; r < 4; ++r) {
                const int row = m0 + w * 32 + mi * 16 + quad * 4 + r;
                float v = acc[mi][ni][r];
                if (R) v += R[(size_t)row * 1024 + col];
                C[(size_t)row * 1024 + col] = (bf16)v;
            }
        }
    }
}

// ---------------------------------------------------------------------------
// Flash attention (r2 known-good version). O written IN-PLACE over QP.
// No running max (|score| <~ 1.5), deferred denominator, wave-local P sync.
// sK0/sK1 bank-swizzled like the GEMM; sVt/sP stride-72 conflict-free.
// ---------------------------------------------------------------------------
__global__ __launch_bounds__(256) void attn_kernel(
    bf16* __restrict__ QP, const bf16* __restrict__ KP, const bf16* __restrict__ VP)
{
    const int fs   = blockIdx.y * 8 + blockIdx.x;
    const int xcd  = fs & 7;
    const int slot = fs >> 3;
    const int qt   = slot & 7;
    const int bh   = (xcd << 4) | (slot >> 3);
    const int tb = (bh >> 4) << 10;
    const int fb = (bh & 15) << 6;

    __shared__ __attribute__((aligned(16))) bf16 sK0[64 * 32];
    __shared__ __attribute__((aligned(16))) bf16 sK1[64 * 32];
    __shared__ __attribute__((aligned(16))) bf16 sVt[64 * 72];
    __shared__ __attribute__((aligned(16))) bf16 sP[4][32 * 72];

    const int t    = threadIdx.x;
    const int w    = t >> 6;
    const int lane = t & 63;
    const int l16  = lane & 15;
    const int quad = lane >> 4;

    const int sgr = ((t & 3) ^ ((t >> 3) & 3)) * 8;       // staging granule (swizzled)
    const int qs  = (quad ^ ((l16 >> 1) & 3)) * 8;        // frag-read slot

    bf16x8 qf[2][2];
#pragma unroll
    for (int mi = 0; mi < 2; ++mi)
#pragma unroll
        for (int kd = 0; kd < 2; ++kd)
            qf[mi][kd] = *(const bf16x8*)&QP[(size_t)(tb + qt * 128 + w * 32 + mi * 16 + l16) * 1024
                                            + fb + kd * 32 + quad * 8];

    f32x4 oacc[2][4];
#pragma unroll
    for (int i = 0; i < 2; ++i)
#pragma unroll
        for (int j = 0; j < 4; ++j)
            oacc[i][j] = (f32x4){0.f, 0.f, 0.f, 0.f};
    float psum[2][4];
#pragma unroll
    for (int i = 0; i < 2; ++i)
#pragma unroll
        for (int r = 0; r < 4; ++r) psum[i][r] = 0.f;

    for (int kt = 0; kt < 16; ++kt) {
        const bf16* kRow = KP + (size_t)(tb + kt * 64 + (t >> 2)) * 1024 + fb + sgr;
        const bf16x8 vk0 = *(const bf16x8*)(kRow);
        const bf16x8 vk1 = *(const bf16x8*)(kRow + 32);
        const bf16* vRow = VP + (size_t)(tb + kt * 64 + lane) * 1024 + fb;
        const bf16x8 vv0 = *(const bf16x8*)(vRow + w * 8);
        const bf16x8 vv1 = *(const bf16x8*)(vRow + (w + 4) * 8);

        __syncthreads();
        *(bf16x8*)&sK0[t * 8] = vk0;
        *(bf16x8*)&sK1[t * 8] = vk1;
#pragma unroll
        for (int j = 0; j < 8; ++j) sVt[(w * 8 + j) * 72 + lane]       = vv0[j];
#pragma unroll
        for (int j = 0; j < 8; ++j) sVt[((w + 4) * 8 + j) * 72 + lane] = vv1[j];
        __syncthreads();

        bf16x8 kf[4][2];
#pragma unroll
        for (int ni = 0; ni < 4; ++ni) {
            kf[ni][0] = *(const bf16x8*)&sK0[(ni * 16 + l16) * 32 + qs];
            kf[ni][1] = *(const bf16x8*)&sK1[(ni * 16 + l16) * 32 + qs];
        }
        f32x4 sfr[2][4];
#pragma unroll
        for (int mi = 0; mi < 2; ++mi)
#pragma unroll
            for (int ni = 0; ni < 4; ++ni) {
                f32x4 a = (f32x4){0.f, 0.f, 0.f, 0.f};
                a = __builtin_amdgcn_mfma_f32_16x16x32_bf16(qf[mi][0], kf[ni][0], a, 0, 0, 0);
                a = __builtin_amdgcn_mfma_f32_16x16x32_bf16(qf[mi][1], kf[ni][1], a, 0, 0, 0);
                sfr[mi][ni] = a * 0.125f;
            }

        // p = exp(s); accumulate per-lane denominator partials (no shuffles)
#pragma unroll
        for (int mi = 0; mi < 2; ++mi)
#pragma unroll
            for (int ni = 0; ni < 4; ++ni)
#pragma unroll
                for (int r = 0; r < 4; ++r) {
                    const float p = __expf(sfr[mi][ni][r]);
                    sfr[mi][ni][r] = p;
                    psum[mi][r] += p;
                }

        // P: C-layout -> A-operand layout via wave-private LDS strip
        bf16* sPw = &sP[w][0];
#pragma unroll
        for (int mi = 0; mi < 2; ++mi)
#pragma unroll
            for (int ni = 0; ni < 4; ++ni)
#pragma unroll
                for (int r = 0; r < 4; ++r)
                    sPw[(mi * 16 + quad * 4 + r) * 72 + ni * 16 + l16] = (bf16)sfr[mi][ni][r];
        asm volatile("s_waitcnt lgkmcnt(0)" ::: "memory");   // wave-local W->R order

#pragma unroll
        for (int kd = 0; kd < 2; ++kd) {
            bf16x8 pf[2], vf[4];
#pragma unroll
            for (int mi = 0; mi < 2; ++mi)
                pf[mi] = *(const bf16x8*)&sPw[(mi * 16 + l16) * 72 + kd * 32 + quad * 8];
#pragma unroll
            for (int di = 0; di < 4; ++di)
                vf[di] = *(const bf16x8*)&sVt[(di * 16 + l16) * 72 + kd * 32 + quad * 8];
#pragma unroll
            for (int mi = 0; mi < 2; ++mi)
#pragma unroll
                for (int di = 0; di < 4; ++di)
                    oacc[mi][di] = __builtin_amdgcn_mfma_f32_16x16x32_bf16(pf[mi], vf[di], oacc[mi][di], 0, 0, 0);
        }
    }

#pragma unroll
    for (int mi = 0; mi < 2; ++mi) {
#pragma unroll
        for (int r = 0; r < 4; ++r) {
            float l = psum[mi][r];
            l += __shfl_xor(l, 1);
            l += __shfl_xor(l, 2);
            l += __shfl_xor(l, 4);
            l += __shfl_xor(l, 8);
            const float inv = 1.f / l;
            const int row = tb + qt * 128 + w * 32 + mi * 16 + quad * 4 + r;
#pragma unroll
            for (int di = 0; di < 4; ++di) {
                const int col = fb + di * 16 + l16;
                QP[(size_t)row * 1024 + col] = (bf16)(oacc[mi][di][r] * inv);
            }
        }
    }
}

// ---------------------------------------------------------------------------
// LayerNorm: bf16 in, fp32 gamma/beta, fp32 out. One 128-thread block per row.
// ---------------------------------------------------------------------------
__global__ __launch_bounds__(128) void ln_kernel(const bf16* __restrict__ X,
                                                 const float* __restrict__ G,
                                                 const float* __restrict__ Bt,
                                                 float* __restrict__ Y)
{
    const int row = blockIdx.x;
    const int t   = threadIdx.x;
    const size_t base = (size_t)row * 1024 + t * 8;
    const bf16x8 xv = *(const bf16x8*)(X + base);
    float f[8];
    float s = 0.f, s2 = 0.f;
#pragma unroll
    for (int j = 0; j < 8; ++j) { f[j] = (float)xv[j]; s += f[j]; s2 += f[j] * f[j]; }
#pragma unroll
    for (int off = 1; off < 64; off <<= 1) { s += __shfl_xor(s, off); s2 += __shfl_xor(s2, off); }
    __shared__ float ss[2], ssq[2];
    if ((t & 63) == 0) { ss[t >> 6] = s; ssq[t >> 6] = s2; }
    __syncthreads();
    s  = ss[0] + ss[1];
    s2 = ssq[0] + ssq[1];
    const float mu  = s * (1.f / 1024.f);
    const float inv = rsqrtf(s2 * (1.f / 1024.f) - mu * mu + 1e-5f);
    const f32x4 g0 = *(const f32x4*)(G + t * 8);
    const f32x4 g1 = *(const f32x4*)(G + t * 8 + 4);
    const f32x4 b0 = *(const f32x4*)(Bt + t * 8);
    const f32x4 b1 = *(const f32x4*)(Bt + t * 8 + 4);
    f32x4 y0, y1;
#pragma unroll
    for (int j = 0; j < 4; ++j) {
        y0[j] = (f[j]     - mu) * inv * g0[j] + b0[j];
        y1[j] = (f[j + 4] - mu) * inv * g1[j] + b1[j];
    }
    *(f32x4*)(Y + base)     = y0;
    *(f32x4*)(Y + base + 4) = y1;
}

// ---------------------------------------------------------------------------
extern "C" void kernel_launch(void* const* d_in, const int* in_sizes, int n_in,
                              void* d_out, int out_size, void* d_ws, size_t ws_size,
                              hipStream_t stream)
{
    const float* query = (const float*)d_in[0];
    const float* key   = (const float*)d_in[1];
    const float* value = (const float*)d_in[2];
    const float* Wq    = (const float*)d_in[3];
    const float* Wk    = (const float*)d_in[4];
    const float* Wv    = (const float*)d_in[5];
    const float* ipw   = (const float*)d_in[6];
    const float* opw   = (const float*)d_in[7];
    const float* pw    = (const float*)d_in[8];
    const float* gamma = (const float*)d_in[9];
    const float* beta  = (const float*)d_in[10];

    const size_t ACT = (size_t)8192 * 1024;   // act slot: 8.39M elems (16.78 MB)
    const size_t MW  = 1048576;               // weight matrix: 1M elems (2 MB)
    bf16* o0 = (bf16*)d_out;                  // d_out fp32 = 2 bf16 act slots
    bf16* o1 = o0 + ACT;

    dim3 blk(256);
    dim3 g3(16, 64, 3);   // 128x64 tiles: 1024 blocks/slice
    dim3 g1(16, 64, 1);
    dim3 ga(8, 128);

    // Full tier needs 6 weight mats + 2 act slots = 45.6 MB (round 4 proved >=50.3)
    const bool full = ws_size >= (6 * MW + 2 * ACT) * sizeof(bf16);

    if (full) {
        bf16* wq  = (bf16*)d_ws;        // persistent bf16 weights
        bf16* wk  = wq + MW;
        bf16* wqa = wq + 2 * MW;
        bf16* wka = wq + 3 * MW;
        bf16* Fv  = wq + 4 * MW;        // fused Wva@Wv
        bf16* Fo  = wq + 5 * MW;        // fused pw@opw
        bf16* sltA = wq + 6 * MW;       // act slot A
        bf16* sltB = sltA + ACT;        // act slot B
        // transients (dead before slots hold activations)
        bf16* tWva = sltA;              // A-operands for precompute
        bf16* tpw  = sltA + MW;
        bf16* WvT  = sltB;              // transposed B-operands
        bf16* opwT = sltB + MW;

        // 0) weight converts + transposes
        wconv6<<<dim3(512, 1, 6), blk, 0, stream>>>(
            Wq, Wk, ipw, ipw + MW, ipw + 2 * MW, pw,
            wq, wk, wqa, wka, tWva, tpw);
        prepT<<<dim3(16, 16, 2), blk, 0, stream>>>(Wv, opw, WvT, opwT);
        // 1) precompute fused weights: Fv = Wva@Wv, Fo = pw@opw
        gemm_bt<0, 0><<<dim3(16, 8, 2), blk, 0, stream>>>(
            tWva, tpw, tpw, WvT, opwT, opwT, Fv, Fo, Fo, nullptr, 0);
        // 2) q(rope)=sltA, k(rope)=sltB, vp = value@Fv^T = o0 (skips v intermediate)
        gemm_bt<1, 0><<<g3, blk, 0, stream>>>(query, key, value, wq, wk, Fv,
                                              sltA, sltB, o0, nullptr, 0b011);
        // 3) qp = q @ Wqa^T   (sltA -> o1)
        gemm_bt<0, 0><<<g1, blk, 0, stream>>>(sltA, sltA, sltA, wqa, wqa, wqa,
                                              o1, o1, o1, nullptr, 0);
        // 4) kp = k @ Wka^T   (sltB -> sltA)
        gemm_bt<0, 0><<<g1, blk, 0, stream>>>(sltB, sltB, sltB, wka, wka, wka,
                                              sltA, sltA, sltA, nullptr, 0);
        // 5) attention: qp=o1 (O in-place), kp=sltA, vp=o0
        attn_kernel<<<ga, blk, 0, stream>>>(o1, sltA, o0);
        // 6) x = o @ Fo^T + query (o1 -> sltB)  [skips o2 intermediate]
        gemm_bt<0, 0><<<g1, blk, 0, stream>>>(o1, o1, o1, Fo, Fo, Fo,
                                              sltB, sltB, sltB, query, 0);
        // 7) LayerNorm -> d_out fp32
        ln_kernel<<<8192, 128, 0, stream>>>(sltB, gamma, beta, (float*)d_out);
    } else {
        // 33.5 MB fallback: round-3 schedule, fp32 weights, attn in-place
        bf16* b0 = (bf16*)d_ws;
        bf16* b1 = b0 + ACT;
        gemm_bt<1, 1><<<g3, blk, 0, stream>>>(query, key, value, Wq, Wk, Wv,
                                              b0, b1, o0, nullptr, 0b011);
        gemm_bt<0, 1><<<g1, blk, 0, stream>>>(o0, o0, o0, ipw + 2 * MW, ipw, ipw,
                                              o1, o1, o1, nullptr, 0);
        gemm_bt<0, 1><<<g1, blk, 0, stream>>>(b0, b0, b0, ipw, ipw, ipw,
                                              o0, o0, o0, nullptr, 0);
        gemm_bt<0, 1><<<g1, blk, 0, stream>>>(b1, b1, b1, ipw + MW, ipw, ipw,
                                              b0, b0, b0, nullptr, 0);
        attn_kernel<<<ga, blk, 0, stream>>>(o0, b0, o1);   // o -> o0 in-place
        gemm_bt<0, 1><<<g1, blk, 0, stream>>>(o0, o0, o0, opw, opw, opw,
                                              b0, b0, b0, nullptr, 0);
        gemm_bt<0, 1><<<g1, blk, 0, stream>>>(b0, b0, b0, pw, pw, pw,
                                              b1, b1, b1, query, 0);
        ln_kernel<<<8192, 128, 0, stream>>>(b1, gamma, beta, (float*)d_out);
    }
}

// Round 6
// 444.262 us; speedup vs baseline: 1.2366x; 1.0392x over previous
//
#include <hip/hip_runtime.h>
#include <hip/hip_bf16.h>
#include <stdint.h>

typedef __bf16 bf16;
typedef __attribute__((ext_vector_type(8))) __bf16 bf16x8;
typedef __attribute__((ext_vector_type(4))) float f32x4;

#define NEG_LN10K_32 (-0.28782313662425575f)   // -ln(10000)/32

__device__ __forceinline__ bf16x8 cvt8(f32x4 a, f32x4 b) {
    bf16x8 r;
    r[0] = (bf16)a[0]; r[1] = (bf16)a[1]; r[2] = (bf16)a[2]; r[3] = (bf16)a[3];
    r[4] = (bf16)b[0]; r[5] = (bf16)b[1]; r[6] = (bf16)b[2]; r[7] = (bf16)b[3];
    return r;
}

__device__ __forceinline__ void async_copy16(bf16* lds, const bf16* g) {
    __builtin_amdgcn_global_load_lds((const __attribute__((address_space(1))) void*)g,
                                     (__attribute__((address_space(3))) void*)lds, 16, 0, 0);
}

// ---------------------------------------------------------------------------
// Weight convert fp32->bf16, 6 segments of 1M elems. Grid (512,1,6).
// ---------------------------------------------------------------------------
__global__ __launch_bounds__(256) void wconv6(
    const float* __restrict__ s0, const float* __restrict__ s1, const float* __restrict__ s2,
    const float* __restrict__ s3, const float* __restrict__ s4, const float* __restrict__ s5,
    bf16* __restrict__ d0, bf16* __restrict__ d1, bf16* __restrict__ d2,
    bf16* __restrict__ d3, bf16* __restrict__ d4, bf16* __restrict__ d5)
{
    const int z = blockIdx.z;
    const float* src; bf16* dst;
    switch (z) {
        case 0: src = s0; dst = d0; break;
        case 1: src = s1; dst = d1; break;
        case 2: src = s2; dst = d2; break;
        case 3: src = s3; dst = d3; break;
        case 4: src = s4; dst = d4; break;
        default: src = s5; dst = d5; break;
    }
    const size_t i = ((size_t)blockIdx.x * 256 + threadIdx.x) * 8;
    *(bf16x8*)(dst + i) = cvt8(*(const f32x4*)(src + i), *(const f32x4*)(src + i + 4));
}

// ---------------------------------------------------------------------------
// Tiled transpose fp32->bf16: out[j,i] = in[i,j], 1024x1024. Grid (16,16,2).
// ---------------------------------------------------------------------------
__global__ __launch_bounds__(256) void prepT(
    const float* __restrict__ in0, const float* __restrict__ in1,
    bf16* __restrict__ out0, bf16* __restrict__ out1)
{
    const float* in = blockIdx.z ? in1 : in0;
    bf16* out       = blockIdx.z ? out1 : out0;
    __shared__ float tile[64 * 65];
    const int t  = threadIdx.x;
    const int i0 = blockIdx.y * 64, j0 = blockIdx.x * 64;
    const int r  = t >> 2, cg = (t & 3) * 16;
#pragma unroll
    for (int c = 0; c < 16; c += 4) {
        const f32x4 v = *(const f32x4*)(in + (size_t)(i0 + r) * 1024 + j0 + cg + c);
        tile[r * 65 + cg + c + 0] = v[0];
        tile[r * 65 + cg + c + 1] = v[1];
        tile[r * 65 + cg + c + 2] = v[2];
        tile[r * 65 + cg + c + 3] = v[3];
    }
    __syncthreads();
    bf16x8 o0v, o1v;
#pragma unroll
    for (int ii = 0; ii < 8; ++ii) {
        o0v[ii] = (bf16)tile[(cg + ii) * 65 + r];
        o1v[ii] = (bf16)tile[(cg + 8 + ii) * 65 + r];
    }
    bf16* dst = out + (size_t)(j0 + r) * 1024 + i0 + cg;
    *(bf16x8*)dst       = o0v;
    *(bf16x8*)(dst + 8) = o1v;
}

// ---------------------------------------------------------------------------
// GEMM: C[M,1024](bf16) = A @ W^T (+fp32 residual, +fused RoPE).
// 128x128 tile, 4 waves of 64x64, mfma 16x16x32 bf16.
//
// Round 6: BK 32 -> 64. Five rounds of evidence: duration tracks
// (#K-steps per CU) x (fixed cost per step) — occupancy 22..40% had no
// effect; killing conflicts had no effect at BK=32; pipelining that cut
// fixed costs but hurt TLP regressed. BK=64 halves the count of the fixed
// per-step costs (2 barriers + implied vmcnt(0) drain + issue overhead)
// while keeping the r2 structure bit-for-bit: same 2-__syncthreads
// single-buffer schedule, same async global_load_lds staging (linear dest),
// same XCD swizzle, occupancy unchanged (regs bind at 3 waves/SIMD; LDS
// 32KB -> 5 blocks capacity, not binding; m132's BK=128 64KB cliff avoided).
// Swizzle re-derived for 8-granule rows (stride 128B would be 32-way
// conflicted unswizzled): stage source granule (lane&7)^(row&7), frag-read
// slot (kk*4+quad)^(l16&7) -> 2-way residual (free, m136).
// MFMA accumulation order identical to two BK=32 steps -> same absmax.
// ---------------------------------------------------------------------------
template<int AF32, int WF32>
__global__ __launch_bounds__(256) void gemm_bt(
    const void* __restrict__ A0v, const void* __restrict__ A1v, const void* __restrict__ A2v,
    const void* __restrict__ W0v, const void* __restrict__ W1v, const void* __restrict__ W2v,
    bf16* __restrict__ C0, bf16* __restrict__ C1, bf16* __restrict__ C2,
    const float* __restrict__ R0, int rope_mask)
{
    const int z = blockIdx.z;
    const void* Av = (z == 0) ? A0v : ((z == 1) ? A1v : A2v);
    const void* Wp = (z == 0) ? W0v : ((z == 1) ? W1v : W2v);
    bf16*       C  = (z == 0) ? C0 : ((z == 1) ? C1 : C2);
    const float* R = (z == 0) ? R0 : nullptr;
    const bool doRope = ((rope_mask >> z) & 1) != 0;

    __shared__ __attribute__((aligned(16))) bf16 sA[128 * 64];   // 16 KB
    __shared__ __attribute__((aligned(16))) bf16 sB[128 * 64];   // 16 KB

    const int t    = threadIdx.x;
    const int w    = t >> 6;
    const int lane = t & 63;
    const int l16  = lane & 15;
    const int quad = lane >> 4;
    const int wrow = w >> 1;
    const int wcol = w & 1;

    int m0, n0;
    if (gridDim.y == 64) {   // M=8192: XCD stripe swizzle (xcd owns 1024 rows)
        const int fs   = blockIdx.y * 8 + blockIdx.x;
        const int xcd  = fs & 7;
        const int slot = fs >> 3;
        m0 = ((xcd << 3) | (slot >> 3)) * 128;
        n0 = (slot & 7) * 128;
    } else {                 // small (weight-precompute) grids: plain mapping
        m0 = blockIdx.y * 128;
        n0 = blockIdx.x * 128;
    }

    // --- async staging map (linear LDS dest, swizzled global source) ---
    // granule gi = (c*4 + w)*64 + lane, c=0..3; row = gi>>3 = (c*4+w)*8 + (lane>>3),
    // lds slot = gi&7 = lane&7; source col granule = (lane&7) ^ (row&7),
    // row&7 = lane>>3 (block part is 0 mod 8).
    const int aLane = (int)(lane >> 3) * 1024 + (((lane & 7) ^ (lane >> 3)) << 3);
    // frag-read slot granule: (kk*4+quad) ^ (row&7), row&7 = l16&7 (per-lane const)
    const int qs0 = ((quad    ) ^ (l16 & 7)) * 8;   // kk = 0
    const int qs1 = ((quad + 4) ^ (l16 & 7)) * 8;   // kk = 1

    // --- reg staging map (fp32 operands): thread owns 4 consecutive granules
    // gi = t*4+j  ->  one row = t>>1, slots (t&1)*4+j, swizzled source cols.
    const int rRow = t >> 1;
    int rCol[4];
#pragma unroll
    for (int j = 0; j < 4; ++j)
        rCol[j] = ((((t & 1) * 4 + j) ^ (rRow & 7)) << 3);

    f32x4 arg[8], brg[8];

    auto loadAreg = [&](int k0) {
        const float* g = (const float*)Av + (size_t)(m0 + rRow) * 1024 + k0;
#pragma unroll
        for (int j = 0; j < 4; ++j) {
            arg[2 * j]     = *(const f32x4*)(g + rCol[j]);
            arg[2 * j + 1] = *(const f32x4*)(g + rCol[j] + 4);
        }
    };
    auto writeAreg = [&]() {
#pragma unroll
        for (int j = 0; j < 4; ++j)
            *(bf16x8*)&sA[t * 32 + j * 8] = cvt8(arg[2 * j], arg[2 * j + 1]);
    };
    auto loadBreg = [&](int k0) {
        const float* g = (const float*)Wp + (size_t)(n0 + rRow) * 1024 + k0;
#pragma unroll
        for (int j = 0; j < 4; ++j) {
            brg[2 * j]     = *(const f32x4*)(g + rCol[j]);
            brg[2 * j + 1] = *(const f32x4*)(g + rCol[j] + 4);
        }
    };
    auto writeBreg = [&]() {
#pragma unroll
        for (int j = 0; j < 4; ++j)
            *(bf16x8*)&sB[t * 32 + j * 8] = cvt8(brg[2 * j], brg[2 * j + 1]);
    };
    auto stageAasync = [&](int k0) {
        const bf16* g = (const bf16*)Av + (size_t)m0 * 1024 + aLane + k0;
#pragma unroll
        for (int c = 0; c < 4; ++c)
            async_copy16(sA + (c * 4 + w) * 512, g + (size_t)(c * 4 + w) * 8 * 1024);
    };
    auto stageBasync = [&](int k0) {
        const bf16* g = (const bf16*)Wp + (size_t)n0 * 1024 + aLane + k0;
#pragma unroll
        for (int c = 0; c < 4; ++c)
            async_copy16(sB + (c * 4 + w) * 512, g + (size_t)(c * 4 + w) * 8 * 1024);
    };

    f32x4 acc[4][4];
#pragma unroll
    for (int i = 0; i < 4; ++i)
#pragma unroll
        for (int j = 0; j < 4; ++j)
            acc[i][j] = (f32x4){0.f, 0.f, 0.f, 0.f};

    for (int k0 = 0; k0 < 1024; k0 += 64) {
        if (AF32) loadAreg(k0);
        if (WF32) loadBreg(k0);
        __syncthreads();
        if (AF32) writeAreg(); else stageAasync(k0);
        if (WF32) writeBreg(); else stageBasync(k0);
        __syncthreads();

#pragma unroll
        for (int kk = 0; kk < 2; ++kk) {
            const int qs = kk ? qs1 : qs0;
            bf16x8 af[4], bw[4];
#pragma unroll
            for (int mi = 0; mi < 4; ++mi)
                af[mi] = *(const bf16x8*)&sA[(wrow * 64 + mi * 16 + l16) * 64 + qs];
#pragma unroll
            for (int ni = 0; ni < 4; ++ni)
                bw[ni] = *(const bf16x8*)&sB[(wcol * 64 + ni * 16 + l16) * 64 + qs];
#pragma unroll
            for (int mi = 0; mi < 4; ++mi)
#pragma unroll
                for (int ni = 0; ni < 4; ++ni)
                    acc[mi][ni] = __builtin_amdgcn_mfma_f32_16x16x32_bf16(af[mi], bw[ni], acc[mi][ni], 0, 0, 0);
        }
    }

    if (doRope) {
        const float bb = (float)(m0 >> 10);
        float s0, c0v, s1, c1v;
        sincosf(bb * expf((float)l16 * NEG_LN10K_32), &s0, &c0v);
        sincosf(bb * expf((float)(16 + l16) * NEG_LN10K_32), &s1, &c1v);
#pragma unroll
        for (int mi = 0; mi < 4; ++mi) {
#pragma unroll
            for (int r = 0; r < 4; ++r) {
                float x1 = acc[mi][0][r], x2 = acc[mi][2][r];
                acc[mi][0][r] = x1 * c0v - x2 * s0;
                acc[mi][2][r] = x2 * c0v + x1 * s0;
                x1 = acc[mi][1][r]; x2 = acc[mi][3][r];
                acc[mi][1][r] = x1 * c1v - x2 * s1;
                acc[mi][3][r] = x2 * c1v + x1 * s1;
            }
        }
    }

#pragma unroll
    for (int mi = 0; mi < 4; ++mi) {
#pragma unroll
        for (int ni = 0; ni < 4; ++ni) {
            const int col = n0 + wcol * 64 + ni * 16 + l16;
#pragma unroll
            for (int r = 0; r < 4; ++r) {
                const int row = m0 + wrow * 64 + mi * 16 + quad * 4 + r;
                float v = acc[mi][ni][r];
                if (R) v += R[(size_t)row * 1024 + col];
                C[(size_t)row * 1024 + col] = (bf16)v;
            }
        }
    }
}

// ---------------------------------------------------------------------------
// Flash attention (r2 known-good version). O written IN-PLACE over QP.
// No running max (|score| <~ 1.5), deferred denominator, wave-local P sync.
// sK0/sK1 bank-swizzled; sVt/sP stride-72 conflict-free.
// ---------------------------------------------------------------------------
__global__ __launch_bounds__(256) void attn_kernel(
    bf16* __restrict__ QP, const bf16* __restrict__ KP, const bf16* __restrict__ VP)
{
    const int fs   = blockIdx.y * 8 + blockIdx.x;
    const int xcd  = fs & 7;
    const int slot = fs >> 3;
    const int qt   = slot & 7;
    const int bh   = (xcd << 4) | (slot >> 3);
    const int tb = (bh >> 4) << 10;
    const int fb = (bh & 15) << 6;

    __shared__ __attribute__((aligned(16))) bf16 sK0[64 * 32];
    __shared__ __attribute__((aligned(16))) bf16 sK1[64 * 32];
    __shared__ __attribute__((aligned(16))) bf16 sVt[64 * 72];
    __shared__ __attribute__((aligned(16))) bf16 sP[4][32 * 72];

    const int t    = threadIdx.x;
    const int w    = t >> 6;
    const int lane = t & 63;
    const int l16  = lane & 15;
    const int quad = lane >> 4;

    const int sgr = ((t & 3) ^ ((t >> 3) & 3)) * 8;       // staging granule (swizzled)
    const int qs  = (quad ^ ((l16 >> 1) & 3)) * 8;        // frag-read slot

    bf16x8 qf[2][2];
#pragma unroll
    for (int mi = 0; mi < 2; ++mi)
#pragma unroll
        for (int kd = 0; kd < 2; ++kd)
            qf[mi][kd] = *(const bf16x8*)&QP[(size_t)(tb + qt * 128 + w * 32 + mi * 16 + l16) * 1024
                                            + fb + kd * 32 + quad * 8];

    f32x4 oacc[2][4];
#pragma unroll
    for (int i = 0; i < 2; ++i)
#pragma unroll
        for (int j = 0; j < 4; ++j)
            oacc[i][j] = (f32x4){0.f, 0.f, 0.f, 0.f};
    float psum[2][4];
#pragma unroll
    for (int i = 0; i < 2; ++i)
#pragma unroll
        for (int r = 0; r < 4; ++r) psum[i][r] = 0.f;

    for (int kt = 0; kt < 16; ++kt) {
        const bf16* kRow = KP + (size_t)(tb + kt * 64 + (t >> 2)) * 1024 + fb + sgr;
        const bf16x8 vk0 = *(const bf16x8*)(kRow);
        const bf16x8 vk1 = *(const bf16x8*)(kRow + 32);
        const bf16* vRow = VP + (size_t)(tb + kt * 64 + lane) * 1024 + fb;
        const bf16x8 vv0 = *(const bf16x8*)(vRow + w * 8);
        const bf16x8 vv1 = *(const bf16x8*)(vRow + (w + 4) * 8);

        __syncthreads();
        *(bf16x8*)&sK0[t * 8] = vk0;
        *(bf16x8*)&sK1[t * 8] = vk1;
#pragma unroll
        for (int j = 0; j < 8; ++j) sVt[(w * 8 + j) * 72 + lane]       = vv0[j];
#pragma unroll
        for (int j = 0; j < 8; ++j) sVt[((w + 4) * 8 + j) * 72 + lane] = vv1[j];
        __syncthreads();

        bf16x8 kf[4][2];
#pragma unroll
        for (int ni = 0; ni < 4; ++ni) {
            kf[ni][0] = *(const bf16x8*)&sK0[(ni * 16 + l16) * 32 + qs];
            kf[ni][1] = *(const bf16x8*)&sK1[(ni * 16 + l16) * 32 + qs];
        }
        f32x4 sfr[2][4];
#pragma unroll
        for (int mi = 0; mi < 2; ++mi)
#pragma unroll
            for (int ni = 0; ni < 4; ++ni) {
                f32x4 a = (f32x4){0.f, 0.f, 0.f, 0.f};
                a = __builtin_amdgcn_mfma_f32_16x16x32_bf16(qf[mi][0], kf[ni][0], a, 0, 0, 0);
                a = __builtin_amdgcn_mfma_f32_16x16x32_bf16(qf[mi][1], kf[ni][1], a, 0, 0, 0);
                sfr[mi][ni] = a * 0.125f;
            }

        // p = exp(s); accumulate per-lane denominator partials (no shuffles)
#pragma unroll
        for (int mi = 0; mi < 2; ++mi)
#pragma unroll
            for (int ni = 0; ni < 4; ++ni)
#pragma unroll
                for (int r = 0; r < 4; ++r) {
                    const float p = __expf(sfr[mi][ni][r]);
                    sfr[mi][ni][r] = p;
                    psum[mi][r] += p;
                }

        // P: C-layout -> A-operand layout via wave-private LDS strip
        bf16* sPw = &sP[w][0];
#pragma unroll
        for (int mi = 0; mi < 2; ++mi)
#pragma unroll
            for (int ni = 0; ni < 4; ++ni)
#pragma unroll
                for (int r = 0; r < 4; ++r)
                    sPw[(mi * 16 + quad * 4 + r) * 72 + ni * 16 + l16] = (bf16)sfr[mi][ni][r];
        asm volatile("s_waitcnt lgkmcnt(0)" ::: "memory");   // wave-local W->R order

#pragma unroll
        for (int kd = 0; kd < 2; ++kd) {
            bf16x8 pf[2], vf[4];
#pragma unroll
            for (int mi = 0; mi < 2; ++mi)
                pf[mi] = *(const bf16x8*)&sPw[(mi * 16 + l16) * 72 + kd * 32 + quad * 8];
#pragma unroll
            for (int di = 0; di < 4; ++di)
                vf[di] = *(const bf16x8*)&sVt[(di * 16 + l16) * 72 + kd * 32 + quad * 8];
#pragma unroll
            for (int mi = 0; mi < 2; ++mi)
#pragma unroll
                for (int di = 0; di < 4; ++di)
                    oacc[mi][di] = __builtin_amdgcn_mfma_f32_16x16x32_bf16(pf[mi], vf[di], oacc[mi][di], 0, 0, 0);
        }
    }

#pragma unroll
    for (int mi = 0; mi < 2; ++mi) {
#pragma unroll
        for (int r = 0; r < 4; ++r) {
            float l = psum[mi][r];
            l += __shfl_xor(l, 1);
            l += __shfl_xor(l, 2);
            l += __shfl_xor(l, 4);
            l += __shfl_xor(l, 8);
            const float inv = 1.f / l;
            const int row = tb + qt * 128 + w * 32 + mi * 16 + quad * 4 + r;
#pragma unroll
            for (int di = 0; di < 4; ++di) {
                const int col = fb + di * 16 + l16;
                QP[(size_t)row * 1024 + col] = (bf16)(oacc[mi][di][r] * inv);
            }
        }
    }
}

// ---------------------------------------------------------------------------
// LayerNorm: bf16 in, fp32 gamma/beta, fp32 out. One 128-thread block per row.
// ---------------------------------------------------------------------------
__global__ __launch_bounds__(128) void ln_kernel(const bf16* __restrict__ X,
                                                 const float* __restrict__ G,
                                                 const float* __restrict__ Bt,
                                                 float* __restrict__ Y)
{
    const int row = blockIdx.x;
    const int t   = threadIdx.x;
    const size_t base = (size_t)row * 1024 + t * 8;
    const bf16x8 xv = *(const bf16x8*)(X + base);
    float f[8];
    float s = 0.f, s2 = 0.f;
#pragma unroll
    for (int j = 0; j < 8; ++j) { f[j] = (float)xv[j]; s += f[j]; s2 += f[j] * f[j]; }
#pragma unroll
    for (int off = 1; off < 64; off <<= 1) { s += __shfl_xor(s, off); s2 += __shfl_xor(s2, off); }
    __shared__ float ss[2], ssq[2];
    if ((t & 63) == 0) { ss[t >> 6] = s; ssq[t >> 6] = s2; }
    __syncthreads();
    s  = ss[0] + ss[1];
    s2 = ssq[0] + ssq[1];
    const float mu  = s * (1.f / 1024.f);
    const float inv = rsqrtf(s2 * (1.f / 1024.f) - mu * mu + 1e-5f);
    const f32x4 g0 = *(const f32x4*)(G + t * 8);
    const f32x4 g1 = *(const f32x4*)(G + t * 8 + 4);
    const f32x4 b0 = *(const f32x4*)(Bt + t * 8);
    const f32x4 b1 = *(const f32x4*)(Bt + t * 8 + 4);
    f32x4 y0, y1;
#pragma unroll
    for (int j = 0; j < 4; ++j) {
        y0[j] = (f[j]     - mu) * inv * g0[j] + b0[j];
        y1[j] = (f[j + 4] - mu) * inv * g1[j] + b1[j];
    }
    *(f32x4*)(Y + base)     = y0;
    *(f32x4*)(Y + base + 4) = y1;
}

// ---------------------------------------------------------------------------
extern "C" void kernel_launch(void* const* d_in, const int* in_sizes, int n_in,
                              void* d_out, int out_size, void* d_ws, size_t ws_size,
                              hipStream_t stream)
{
    const float* query = (const float*)d_in[0];
    const float* key   = (const float*)d_in[1];
    const float* value = (const float*)d_in[2];
    const float* Wq    = (const float*)d_in[3];
    const float* Wk    = (const float*)d_in[4];
    const float* Wv    = (const float*)d_in[5];
    const float* ipw   = (const float*)d_in[6];
    const float* opw   = (const float*)d_in[7];
    const float* pw    = (const float*)d_in[8];
    const float* gamma = (const float*)d_in[9];
    const float* beta  = (const float*)d_in[10];

    const size_t ACT = (size_t)8192 * 1024;   // act slot: 8.39M elems (16.78 MB)
    const size_t MW  = 1048576;               // weight matrix: 1M elems (2 MB)
    bf16* o0 = (bf16*)d_out;                  // d_out fp32 = 2 bf16 act slots
    bf16* o1 = o0 + ACT;

    dim3 blk(256);
    dim3 g3(8, 64, 3);
    dim3 g1(8, 64, 1);
    dim3 ga(8, 128);

    // Full tier needs 6 weight mats + 2 act slots = 45.6 MB (round 4 proved >=50.3)
    const bool full = ws_size >= (6 * MW + 2 * ACT) * sizeof(bf16);

    if (full) {
        bf16* wq  = (bf16*)d_ws;        // persistent bf16 weights
        bf16* wk  = wq + MW;
        bf16* wqa = wq + 2 * MW;
        bf16* wka = wq + 3 * MW;
        bf16* Fv  = wq + 4 * MW;        // fused Wva@Wv
        bf16* Fo  = wq + 5 * MW;        // fused pw@opw
        bf16* sltA = wq + 6 * MW;       // act slot A
        bf16* sltB = sltA + ACT;        // act slot B
        // transients (dead before slots hold activations)
        bf16* tWva = sltA;              // A-operands for precompute
        bf16* tpw  = sltA + MW;
        bf16* WvT  = sltB;              // transposed B-operands
        bf16* opwT = sltB + MW;

        // 0) weight converts + transposes
        wconv6<<<dim3(512, 1, 6), blk, 0, stream>>>(
            Wq, Wk, ipw, ipw + MW, ipw + 2 * MW, pw,
            wq, wk, wqa, wka, tWva, tpw);
        prepT<<<dim3(16, 16, 2), blk, 0, stream>>>(Wv, opw, WvT, opwT);
        // 1) precompute fused weights: Fv = Wva@Wv, Fo = pw@opw
        gemm_bt<0, 0><<<dim3(8, 8, 2), blk, 0, stream>>>(
            tWva, tpw, tpw, WvT, opwT, opwT, Fv, Fo, Fo, nullptr, 0);
        // 2) q(rope)=sltA, k(rope)=sltB, vp = value@Fv^T = o0 (skips v intermediate)
        gemm_bt<1, 0><<<g3, blk, 0, stream>>>(query, key, value, wq, wk, Fv,
                                              sltA, sltB, o0, nullptr, 0b011);
        // 3) qp = q @ Wqa^T   (sltA -> o1)
        gemm_bt<0, 0><<<g1, blk, 0, stream>>>(sltA, sltA, sltA, wqa, wqa, wqa,
                                              o1, o1, o1, nullptr, 0);
        // 4) kp = k @ Wka^T   (sltB -> sltA)
        gemm_bt<0, 0><<<g1, blk, 0, stream>>>(sltB, sltB, sltB, wka, wka, wka,
                                              sltA, sltA, sltA, nullptr, 0);
        // 5) attention: qp=o1 (O in-place), kp=sltA, vp=o0
        attn_kernel<<<ga, blk, 0, stream>>>(o1, sltA, o0);
        // 6) x = o @ Fo^T + query (o1 -> sltB)  [skips o2 intermediate]
        gemm_bt<0, 0><<<g1, blk, 0, stream>>>(o1, o1, o1, Fo, Fo, Fo,
                                              sltB, sltB, sltB, query, 0);
        // 7) LayerNorm -> d_out fp32
        ln_kernel<<<8192, 128, 0, stream>>>(sltB, gamma, beta, (float*)d_out);
    } else {
        // 33.5 MB fallback: round-3 schedule, fp32 weights, attn in-place
        bf16* b0 = (bf16*)d_ws;
        bf16* b1 = b0 + ACT;
        gemm_bt<1, 1><<<g3, blk, 0, stream>>>(query, key, value, Wq, Wk, Wv,
                                              b0, b1, o0, nullptr, 0b011);
        gemm_bt<0, 1><<<g1, blk, 0, stream>>>(o0, o0, o0, ipw + 2 * MW, ipw, ipw,
                                              o1, o1, o1, nullptr, 0);
        gemm_bt<0, 1><<<g1, blk, 0, stream>>>(b0, b0, b0, ipw, ipw, ipw,
                                              o0, o0, o0, nullptr, 0);
        gemm_bt<0, 1><<<g1, blk, 0, stream>>>(b1, b1, b1, ipw + MW, ipw, ipw,
                                              b0, b0, b0, nullptr, 0);
        attn_kernel<<<ga, blk, 0, stream>>>(o0, b0, o1);   // o -> o0 in-place
        gemm_bt<0, 1><<<g1, blk, 0, stream>>>(o0, o0, o0, opw, opw, opw,
                                              b0, b0, b0, nullptr, 0);
        gemm_bt<0, 1><<<g1, blk, 0, stream>>>(b0, b0, b0, pw, pw, pw,
                                              b1, b1, b1, query, 0);
        ln_kernel<<<8192, 128, 0, stream>>>(b1, gamma, beta, (float*)d_out);
    }
}

// Round 7
// 422.499 us; speedup vs baseline: 1.3003x; 1.0515x over previous
//
#include <hip/hip_runtime.h>
#include <hip/hip_bf16.h>
#include <stdint.h>

typedef __bf16 bf16;
typedef __attribute__((ext_vector_type(8))) __bf16 bf16x8;
typedef __attribute__((ext_vector_type(4))) float f32x4;

#define NEG_LN10K_32 (-0.28782313662425575f)   // -ln(10000)/32

__device__ __forceinline__ bf16x8 cvt8(f32x4 a, f32x4 b) {
    bf16x8 r;
    r[0] = (bf16)a[0]; r[1] = (bf16)a[1]; r[2] = (bf16)a[2]; r[3] = (bf16)a[3];
    r[4] = (bf16)b[0]; r[5] = (bf16)b[1]; r[6] = (bf16)b[2]; r[7] = (bf16)b[3];
    return r;
}

__device__ __forceinline__ void async_copy16(bf16* lds, const bf16* g) {
    __builtin_amdgcn_global_load_lds((const __attribute__((address_space(1))) void*)g,
                                     (__attribute__((address_space(3))) void*)lds, 16, 0, 0);
}

// ---------------------------------------------------------------------------
// Weight convert fp32->bf16, 6 segments of 1M elems. Grid (512,1,6).
// ---------------------------------------------------------------------------
__global__ __launch_bounds__(256) void wconv6(
    const float* __restrict__ s0, const float* __restrict__ s1, const float* __restrict__ s2,
    const float* __restrict__ s3, const float* __restrict__ s4, const float* __restrict__ s5,
    bf16* __restrict__ d0, bf16* __restrict__ d1, bf16* __restrict__ d2,
    bf16* __restrict__ d3, bf16* __restrict__ d4, bf16* __restrict__ d5)
{
    const int z = blockIdx.z;
    const float* src; bf16* dst;
    switch (z) {
        case 0: src = s0; dst = d0; break;
        case 1: src = s1; dst = d1; break;
        case 2: src = s2; dst = d2; break;
        case 3: src = s3; dst = d3; break;
        case 4: src = s4; dst = d4; break;
        default: src = s5; dst = d5; break;
    }
    const size_t i = ((size_t)blockIdx.x * 256 + threadIdx.x) * 8;
    *(bf16x8*)(dst + i) = cvt8(*(const f32x4*)(src + i), *(const f32x4*)(src + i + 4));
}

// ---------------------------------------------------------------------------
// Tiled transpose fp32->bf16: out[j,i] = in[i,j], 1024x1024. Grid (16,16,2).
// ---------------------------------------------------------------------------
__global__ __launch_bounds__(256) void prepT(
    const float* __restrict__ in0, const float* __restrict__ in1,
    bf16* __restrict__ out0, bf16* __restrict__ out1)
{
    const float* in = blockIdx.z ? in1 : in0;
    bf16* out       = blockIdx.z ? out1 : out0;
    __shared__ float tile[64 * 65];
    const int t  = threadIdx.x;
    const int i0 = blockIdx.y * 64, j0 = blockIdx.x * 64;
    const int r  = t >> 2, cg = (t & 3) * 16;
#pragma unroll
    for (int c = 0; c < 16; c += 4) {
        const f32x4 v = *(const f32x4*)(in + (size_t)(i0 + r) * 1024 + j0 + cg + c);
        tile[r * 65 + cg + c + 0] = v[0];
        tile[r * 65 + cg + c + 1] = v[1];
        tile[r * 65 + cg + c + 2] = v[2];
        tile[r * 65 + cg + c + 3] = v[3];
    }
    __syncthreads();
    bf16x8 o0v, o1v;
#pragma unroll
    for (int ii = 0; ii < 8; ++ii) {
        o0v[ii] = (bf16)tile[(cg + ii) * 65 + r];
        o1v[ii] = (bf16)tile[(cg + 8 + ii) * 65 + r];
    }
    bf16* dst = out + (size_t)(j0 + r) * 1024 + i0 + cg;
    *(bf16x8*)dst       = o0v;
    *(bf16x8*)(dst + 8) = o1v;
}

// ---------------------------------------------------------------------------
// GEMM: C[M,1024](bf16) = A @ W^T (+fp32 residual, +fused RoPE).
// 128x128 tile, 4 waves of 64x64, mfma 16x16x32 bf16.
//
// Round 7: BK=64 via TWO stride-64B sub-buffers. r6's flat [128][64] layout
// made banks row-independent (row*32 == 0 mod 32) -> unavoidable 8-way read
// conflict (measured 9.4M). Splitting each K-tile into two [128][32] halves
// restores r2's exact geometry (measured 0 conflicts) while keeping r6's
// halved barrier count (one __syncthreads pair per 64-K step), which r6
// proved is the lever (total improved despite the conflict bug).
// Staging: r2's pre-swizzled global source granule (t&3)^((t>>3)&3), linear
// LDS dest; frag-read slot quad^((l16>>1)&3). AF32/WF32 reg-staging = r2's
// pattern doubled. Accumulation order bit-identical to two BK=32 steps.
// ---------------------------------------------------------------------------
template<int AF32, int WF32>
__global__ __launch_bounds__(256) void gemm_bt(
    const void* __restrict__ A0v, const void* __restrict__ A1v, const void* __restrict__ A2v,
    const void* __restrict__ W0v, const void* __restrict__ W1v, const void* __restrict__ W2v,
    bf16* __restrict__ C0, bf16* __restrict__ C1, bf16* __restrict__ C2,
    const float* __restrict__ R0, int rope_mask)
{
    const int z = blockIdx.z;
    const void* Av = (z == 0) ? A0v : ((z == 1) ? A1v : A2v);
    const void* Wp = (z == 0) ? W0v : ((z == 1) ? W1v : W2v);
    bf16*       C  = (z == 0) ? C0 : ((z == 1) ? C1 : C2);
    const float* R = (z == 0) ? R0 : nullptr;
    const bool doRope = ((rope_mask >> z) & 1) != 0;

    __shared__ __attribute__((aligned(16))) bf16 sA[2][128 * 32];   // 2 x 8 KB
    __shared__ __attribute__((aligned(16))) bf16 sB[2][128 * 32];   // 2 x 8 KB

    const int t    = threadIdx.x;
    const int w    = t >> 6;
    const int lane = t & 63;
    const int l16  = lane & 15;
    const int quad = lane >> 4;
    const int wrow = w >> 1;
    const int wcol = w & 1;

    int m0, n0;
    if (gridDim.y == 64) {   // M=8192: XCD stripe swizzle (xcd owns 1024 rows)
        const int fs   = blockIdx.y * 8 + blockIdx.x;
        const int xcd  = fs & 7;
        const int slot = fs >> 3;
        m0 = ((xcd << 3) | (slot >> 3)) * 128;
        n0 = (slot & 7) * 128;
    } else {                 // small (weight-precompute) grids: plain mapping
        m0 = blockIdx.y * 128;
        n0 = blockIdx.x * 128;
    }

    // staging offsets: global source granule pre-swizzled (LDS dest linear)
    const int sgr = ((t & 3) ^ ((t >> 3) & 3)) * 8;
    const size_t aOff = (size_t)(m0 + (t >> 2)) * 1024 + sgr;
    const size_t wOff = (size_t)(n0 + (t >> 2)) * 1024 + sgr;
    // frag-read slot: quad ^ (row>>1)&3  (per-lane constant; r2-proven 0-conflict)
    const int qs = (quad ^ ((l16 >> 1) & 3)) * 8;

    f32x4 acc[4][4];
#pragma unroll
    for (int i = 0; i < 4; ++i)
#pragma unroll
        for (int j = 0; j < 4; ++j)
            acc[i][j] = (f32x4){0.f, 0.f, 0.f, 0.f};

    for (int k0 = 0; k0 < 1024; k0 += 64) {
        bf16x8 va[4], vb[4];
        if (AF32) {
            const float* g = (const float*)Av;
            va[0] = cvt8(*(const f32x4*)(g + aOff + k0),              *(const f32x4*)(g + aOff + k0 + 4));
            va[1] = cvt8(*(const f32x4*)(g + aOff + 65536 + k0),      *(const f32x4*)(g + aOff + 65536 + k0 + 4));
            va[2] = cvt8(*(const f32x4*)(g + aOff + k0 + 32),         *(const f32x4*)(g + aOff + k0 + 36));
            va[3] = cvt8(*(const f32x4*)(g + aOff + 65536 + k0 + 32), *(const f32x4*)(g + aOff + 65536 + k0 + 36));
        }
        if (WF32) {
            const float* g = (const float*)Wp;
            vb[0] = cvt8(*(const f32x4*)(g + wOff + k0),              *(const f32x4*)(g + wOff + k0 + 4));
            vb[1] = cvt8(*(const f32x4*)(g + wOff + 65536 + k0),      *(const f32x4*)(g + wOff + 65536 + k0 + 4));
            vb[2] = cvt8(*(const f32x4*)(g + wOff + k0 + 32),         *(const f32x4*)(g + wOff + k0 + 36));
            vb[3] = cvt8(*(const f32x4*)(g + wOff + 65536 + k0 + 32), *(const f32x4*)(g + wOff + 65536 + k0 + 36));
        }
        __syncthreads();
        if (AF32) {
            *(bf16x8*)&sA[0][t * 8]        = va[0];
            *(bf16x8*)&sA[0][t * 8 + 2048] = va[1];
            *(bf16x8*)&sA[1][t * 8]        = va[2];
            *(bf16x8*)&sA[1][t * 8 + 2048] = va[3];
        } else {
            const bf16* g = (const bf16*)Av;
            async_copy16(&sA[0][w * 512],        g + aOff + k0);
            async_copy16(&sA[0][w * 512 + 2048], g + aOff + 65536 + k0);
            async_copy16(&sA[1][w * 512],        g + aOff + k0 + 32);
            async_copy16(&sA[1][w * 512 + 2048], g + aOff + 65536 + k0 + 32);
        }
        if (WF32) {
            *(bf16x8*)&sB[0][t * 8]        = vb[0];
            *(bf16x8*)&sB[0][t * 8 + 2048] = vb[1];
            *(bf16x8*)&sB[1][t * 8]        = vb[2];
            *(bf16x8*)&sB[1][t * 8 + 2048] = vb[3];
        } else {
            const bf16* g = (const bf16*)Wp;
            async_copy16(&sB[0][w * 512],        g + wOff + k0);
            async_copy16(&sB[0][w * 512 + 2048], g + wOff + 65536 + k0);
            async_copy16(&sB[1][w * 512],        g + wOff + k0 + 32);
            async_copy16(&sB[1][w * 512 + 2048], g + wOff + 65536 + k0 + 32);
        }
        __syncthreads();

#pragma unroll
        for (int kk = 0; kk < 2; ++kk) {
            bf16x8 af[4], bw[4];
#pragma unroll
            for (int mi = 0; mi < 4; ++mi)
                af[mi] = *(const bf16x8*)&sA[kk][(wrow * 64 + mi * 16 + l16) * 32 + qs];
#pragma unroll
            for (int ni = 0; ni < 4; ++ni)
                bw[ni] = *(const bf16x8*)&sB[kk][(wcol * 64 + ni * 16 + l16) * 32 + qs];
#pragma unroll
            for (int mi = 0; mi < 4; ++mi)
#pragma unroll
                for (int ni = 0; ni < 4; ++ni)
                    acc[mi][ni] = __builtin_amdgcn_mfma_f32_16x16x32_bf16(af[mi], bw[ni], acc[mi][ni], 0, 0, 0);
        }
    }

    if (doRope) {
        const float bb = (float)(m0 >> 10);
        float s0, c0v, s1, c1v;
        sincosf(bb * expf((float)l16 * NEG_LN10K_32), &s0, &c0v);
        sincosf(bb * expf((float)(16 + l16) * NEG_LN10K_32), &s1, &c1v);
#pragma unroll
        for (int mi = 0; mi < 4; ++mi) {
#pragma unroll
            for (int r = 0; r < 4; ++r) {
                float x1 = acc[mi][0][r], x2 = acc[mi][2][r];
                acc[mi][0][r] = x1 * c0v - x2 * s0;
                acc[mi][2][r] = x2 * c0v + x1 * s0;
                x1 = acc[mi][1][r]; x2 = acc[mi][3][r];
                acc[mi][1][r] = x1 * c1v - x2 * s1;
                acc[mi][3][r] = x2 * c1v + x1 * s1;
            }
        }
    }

#pragma unroll
    for (int mi = 0; mi < 4; ++mi) {
#pragma unroll
        for (int ni = 0; ni < 4; ++ni) {
            const int col = n0 + wcol * 64 + ni * 16 + l16;
#pragma unroll
            for (int r = 0; r < 4; ++r) {
                const int row = m0 + wrow * 64 + mi * 16 + quad * 4 + r;
                float v = acc[mi][ni][r];
                if (R) v += R[(size_t)row * 1024 + col];
                C[(size_t)row * 1024 + col] = (bf16)v;
            }
        }
    }
}

// ---------------------------------------------------------------------------
// Flash attention (r2 known-good version, untouched). O written IN-PLACE over
// QP. No running max (|score| <~ 1.5), deferred denominator, wave-local P
// sync. sK0/sK1 bank-swizzled; sVt/sP stride-72 conflict-free.
// ---------------------------------------------------------------------------
__global__ __launch_bounds__(256) void attn_kernel(
    bf16* __restrict__ QP, const bf16* __restrict__ KP, const bf16* __restrict__ VP)
{
    const int fs   = blockIdx.y * 8 + blockIdx.x;
    const int xcd  = fs & 7;
    const int slot = fs >> 3;
    const int qt   = slot & 7;
    const int bh   = (xcd << 4) | (slot >> 3);
    const int tb = (bh >> 4) << 10;
    const int fb = (bh & 15) << 6;

    __shared__ __attribute__((aligned(16))) bf16 sK0[64 * 32];
    __shared__ __attribute__((aligned(16))) bf16 sK1[64 * 32];
    __shared__ __attribute__((aligned(16))) bf16 sVt[64 * 72];
    __shared__ __attribute__((aligned(16))) bf16 sP[4][32 * 72];

    const int t    = threadIdx.x;
    const int w    = t >> 6;
    const int lane = t & 63;
    const int l16  = lane & 15;
    const int quad = lane >> 4;

    const int sgr = ((t & 3) ^ ((t >> 3) & 3)) * 8;       // staging granule (swizzled)
    const int qs  = (quad ^ ((l16 >> 1) & 3)) * 8;        // frag-read slot

    bf16x8 qf[2][2];
#pragma unroll
    for (int mi = 0; mi < 2; ++mi)
#pragma unroll
        for (int kd = 0; kd < 2; ++kd)
            qf[mi][kd] = *(const bf16x8*)&QP[(size_t)(tb + qt * 128 + w * 32 + mi * 16 + l16) * 1024
                                            + fb + kd * 32 + quad * 8];

    f32x4 oacc[2][4];
#pragma unroll
    for (int i = 0; i < 2; ++i)
#pragma unroll
        for (int j = 0; j < 4; ++j)
            oacc[i][j] = (f32x4){0.f, 0.f, 0.f, 0.f};
    float psum[2][4];
#pragma unroll
    for (int i = 0; i < 2; ++i)
#pragma unroll
        for (int r = 0; r < 4; ++r) psum[i][r] = 0.f;

    for (int kt = 0; kt < 16; ++kt) {
        const bf16* kRow = KP + (size_t)(tb + kt * 64 + (t >> 2)) * 1024 + fb + sgr;
        const bf16x8 vk0 = *(const bf16x8*)(kRow);
        const bf16x8 vk1 = *(const bf16x8*)(kRow + 32);
        const bf16* vRow = VP + (size_t)(tb + kt * 64 + lane) * 1024 + fb;
        const bf16x8 vv0 = *(const bf16x8*)(vRow + w * 8);
        const bf16x8 vv1 = *(const bf16x8*)(vRow + (w + 4) * 8);

        __syncthreads();
        *(bf16x8*)&sK0[t * 8] = vk0;
        *(bf16x8*)&sK1[t * 8] = vk1;
#pragma unroll
        for (int j = 0; j < 8; ++j) sVt[(w * 8 + j) * 72 + lane]       = vv0[j];
#pragma unroll
        for (int j = 0; j < 8; ++j) sVt[((w + 4) * 8 + j) * 72 + lane] = vv1[j];
        __syncthreads();

        bf16x8 kf[4][2];
#pragma unroll
        for (int ni = 0; ni < 4; ++ni) {
            kf[ni][0] = *(const bf16x8*)&sK0[(ni * 16 + l16) * 32 + qs];
            kf[ni][1] = *(const bf16x8*)&sK1[(ni * 16 + l16) * 32 + qs];
        }
        f32x4 sfr[2][4];
#pragma unroll
        for (int mi = 0; mi < 2; ++mi)
#pragma unroll
            for (int ni = 0; ni < 4; ++ni) {
                f32x4 a = (f32x4){0.f, 0.f, 0.f, 0.f};
                a = __builtin_amdgcn_mfma_f32_16x16x32_bf16(qf[mi][0], kf[ni][0], a, 0, 0, 0);
                a = __builtin_amdgcn_mfma_f32_16x16x32_bf16(qf[mi][1], kf[ni][1], a, 0, 0, 0);
                sfr[mi][ni] = a * 0.125f;
            }

        // p = exp(s); accumulate per-lane denominator partials (no shuffles)
#pragma unroll
        for (int mi = 0; mi < 2; ++mi)
#pragma unroll
            for (int ni = 0; ni < 4; ++ni)
#pragma unroll
                for (int r = 0; r < 4; ++r) {
                    const float p = __expf(sfr[mi][ni][r]);
                    sfr[mi][ni][r] = p;
                    psum[mi][r] += p;
                }

        // P: C-layout -> A-operand layout via wave-private LDS strip
        bf16* sPw = &sP[w][0];
#pragma unroll
        for (int mi = 0; mi < 2; ++mi)
#pragma unroll
            for (int ni = 0; ni < 4; ++ni)
#pragma unroll
                for (int r = 0; r < 4; ++r)
                    sPw[(mi * 16 + quad * 4 + r) * 72 + ni * 16 + l16] = (bf16)sfr[mi][ni][r];
        asm volatile("s_waitcnt lgkmcnt(0)" ::: "memory");   // wave-local W->R order

#pragma unroll
        for (int kd = 0; kd < 2; ++kd) {
            bf16x8 pf[2], vf[4];
#pragma unroll
            for (int mi = 0; mi < 2; ++mi)
                pf[mi] = *(const bf16x8*)&sPw[(mi * 16 + l16) * 72 + kd * 32 + quad * 8];
#pragma unroll
            for (int di = 0; di < 4; ++di)
                vf[di] = *(const bf16x8*)&sVt[(di * 16 + l16) * 72 + kd * 32 + quad * 8];
#pragma unroll
            for (int mi = 0; mi < 2; ++mi)
#pragma unroll
                for (int di = 0; di < 4; ++di)
                    oacc[mi][di] = __builtin_amdgcn_mfma_f32_16x16x32_bf16(pf[mi], vf[di], oacc[mi][di], 0, 0, 0);
        }
    }

#pragma unroll
    for (int mi = 0; mi < 2; ++mi) {
#pragma unroll
        for (int r = 0; r < 4; ++r) {
            float l = psum[mi][r];
            l += __shfl_xor(l, 1);
            l += __shfl_xor(l, 2);
            l += __shfl_xor(l, 4);
            l += __shfl_xor(l, 8);
            const float inv = 1.f / l;
            const int row = tb + qt * 128 + w * 32 + mi * 16 + quad * 4 + r;
#pragma unroll
            for (int di = 0; di < 4; ++di) {
                const int col = fb + di * 16 + l16;
                QP[(size_t)row * 1024 + col] = (bf16)(oacc[mi][di][r] * inv);
            }
        }
    }
}

// ---------------------------------------------------------------------------
// LayerNorm: bf16 in, fp32 gamma/beta, fp32 out. One 128-thread block per row.
// ---------------------------------------------------------------------------
__global__ __launch_bounds__(128) void ln_kernel(const bf16* __restrict__ X,
                                                 const float* __restrict__ G,
                                                 const float* __restrict__ Bt,
                                                 float* __restrict__ Y)
{
    const int row = blockIdx.x;
    const int t   = threadIdx.x;
    const size_t base = (size_t)row * 1024 + t * 8;
    const bf16x8 xv = *(const bf16x8*)(X + base);
    float f[8];
    float s = 0.f, s2 = 0.f;
#pragma unroll
    for (int j = 0; j < 8; ++j) { f[j] = (float)xv[j]; s += f[j]; s2 += f[j] * f[j]; }
#pragma unroll
    for (int off = 1; off < 64; off <<= 1) { s += __shfl_xor(s, off); s2 += __shfl_xor(s2, off); }
    __shared__ float ss[2], ssq[2];
    if ((t & 63) == 0) { ss[t >> 6] = s; ssq[t >> 6] = s2; }
    __syncthreads();
    s  = ss[0] + ss[1];
    s2 = ssq[0] + ssq[1];
    const float mu  = s * (1.f / 1024.f);
    const float inv = rsqrtf(s2 * (1.f / 1024.f) - mu * mu + 1e-5f);
    const f32x4 g0 = *(const f32x4*)(G + t * 8);
    const f32x4 g1 = *(const f32x4*)(G + t * 8 + 4);
    const f32x4 b0 = *(const f32x4*)(Bt + t * 8);
    const f32x4 b1 = *(const f32x4*)(Bt + t * 8 + 4);
    f32x4 y0, y1;
#pragma unroll
    for (int j = 0; j < 4; ++j) {
        y0[j] = (f[j]     - mu) * inv * g0[j] + b0[j];
        y1[j] = (f[j + 4] - mu) * inv * g1[j] + b1[j];
    }
    *(f32x4*)(Y + base)     = y0;
    *(f32x4*)(Y + base + 4) = y1;
}

// ---------------------------------------------------------------------------
extern "C" void kernel_launch(void* const* d_in, const int* in_sizes, int n_in,
                              void* d_out, int out_size, void* d_ws, size_t ws_size,
                              hipStream_t stream)
{
    const float* query = (const float*)d_in[0];
    const float* key   = (const float*)d_in[1];
    const float* value = (const float*)d_in[2];
    const float* Wq    = (const float*)d_in[3];
    const float* Wk    = (const float*)d_in[4];
    const float* Wv    = (const float*)d_in[5];
    const float* ipw   = (const float*)d_in[6];
    const float* opw   = (const float*)d_in[7];
    const float* pw    = (const float*)d_in[8];
    const float* gamma = (const float*)d_in[9];
    const float* beta  = (const float*)d_in[10];

    const size_t ACT = (size_t)8192 * 1024;   // act slot: 8.39M elems (16.78 MB)
    const size_t MW  = 1048576;               // weight matrix: 1M elems (2 MB)
    bf16* o0 = (bf16*)d_out;                  // d_out fp32 = 2 bf16 act slots
    bf16* o1 = o0 + ACT;

    dim3 blk(256);
    dim3 g3(8, 64, 3);
    dim3 g1(8, 64, 1);
    dim3 ga(8, 128);

    // Full tier needs 6 weight mats + 2 act slots = 45.6 MB (round 4 proved >=50.3)
    const bool full = ws_size >= (6 * MW + 2 * ACT) * sizeof(bf16);

    if (full) {
        bf16* wq  = (bf16*)d_ws;        // persistent bf16 weights
        bf16* wk  = wq + MW;
        bf16* wqa = wq + 2 * MW;
        bf16* wka = wq + 3 * MW;
        bf16* Fv  = wq + 4 * MW;        // fused Wva@Wv
        bf16* Fo  = wq + 5 * MW;        // fused pw@opw
        bf16* sltA = wq + 6 * MW;       // act slot A
        bf16* sltB = sltA + ACT;        // act slot B
        // transients (dead before slots hold activations)
        bf16* tWva = sltA;              // A-operands for precompute
        bf16* tpw  = sltA + MW;
        bf16* WvT  = sltB;              // transposed B-operands
        bf16* opwT = sltB + MW;

        // 0) weight converts + transposes
        wconv6<<<dim3(512, 1, 6), blk, 0, stream>>>(
            Wq, Wk, ipw, ipw + MW, ipw + 2 * MW, pw,
            wq, wk, wqa, wka, tWva, tpw);
        prepT<<<dim3(16, 16, 2), blk, 0, stream>>>(Wv, opw, WvT, opwT);
        // 1) precompute fused weights: Fv = Wva@Wv, Fo = pw@opw
        gemm_bt<0, 0><<<dim3(8, 8, 2), blk, 0, stream>>>(
            tWva, tpw, tpw, WvT, opwT, opwT, Fv, Fo, Fo, nullptr, 0);
        // 2) q(rope)=sltA, k(rope)=sltB, vp = value@Fv^T = o0 (skips v intermediate)
        gemm_bt<1, 0><<<g3, blk, 0, stream>>>(query, key, value, wq, wk, Fv,
                                              sltA, sltB, o0, nullptr, 0b011);
        // 3) qp = q @ Wqa^T   (sltA -> o1)
        gemm_bt<0, 0><<<g1, blk, 0, stream>>>(sltA, sltA, sltA, wqa, wqa, wqa,
                                              o1, o1, o1, nullptr, 0);
        // 4) kp = k @ Wka^T   (sltB -> sltA)
        gemm_bt<0, 0><<<g1, blk, 0, stream>>>(sltB, sltB, sltB, wka, wka, wka,
                                              sltA, sltA, sltA, nullptr, 0);
        // 5) attention: qp=o1 (O in-place), kp=sltA, vp=o0
        attn_kernel<<<ga, blk, 0, stream>>>(o1, sltA, o0);
        // 6) x = o @ Fo^T + query (o1 -> sltB)  [skips o2 intermediate]
        gemm_bt<0, 0><<<g1, blk, 0, stream>>>(o1, o1, o1, Fo, Fo, Fo,
                                              sltB, sltB, sltB, query, 0);
        // 7) LayerNorm -> d_out fp32
        ln_kernel<<<8192, 128, 0, stream>>>(sltB, gamma, beta, (float*)d_out);
    } else {
        // 33.5 MB fallback: round-3 schedule, fp32 weights, attn in-place
        bf16* b0 = (bf16*)d_ws;
        bf16* b1 = b0 + ACT;
        gemm_bt<1, 1><<<g3, blk, 0, stream>>>(query, key, value, Wq, Wk, Wv,
                                              b0, b1, o0, nullptr, 0b011);
        gemm_bt<0, 1><<<g1, blk, 0, stream>>>(o0, o0, o0, ipw + 2 * MW, ipw, ipw,
                                              o1, o1, o1, nullptr, 0);
        gemm_bt<0, 1><<<g1, blk, 0, stream>>>(b0, b0, b0, ipw, ipw, ipw,
                                              o0, o0, o0, nullptr, 0);
        gemm_bt<0, 1><<<g1, blk, 0, stream>>>(b1, b1, b1, ipw + MW, ipw, ipw,
                                              b0, b0, b0, nullptr, 0);
        attn_kernel<<<ga, blk, 0, stream>>>(o0, b0, o1);   // o -> o0 in-place
        gemm_bt<0, 1><<<g1, blk, 0, stream>>>(o0, o0, o0, opw, opw, opw,
                                              b0, b0, b0, nullptr, 0);
        gemm_bt<0, 1><<<g1, blk, 0, stream>>>(b0, b0, b0, pw, pw, pw,
                                              b1, b1, b1, query, 0);
        ln_kernel<<<8192, 128, 0, stream>>>(b1, gamma, beta, (float*)d_out);
    }
}